// Round 17
// baseline (183.952 us; speedup 1.0000x reference)
//
#include <hip/hip_runtime.h>
#include <hip/hip_bf16.h>

#define N_NODES 50000
#define N_EDGES 1600000
#define ND 16
#define ED 16
#define HID 64
#define M1 (2*ND+ED)   // 48
#define M2 (ND+ED)     // 32
#define N_TILES (N_EDGES / 16)   // 100000
#define WAVES 4
#define TPW_E 16                  // tiles per wave (edge)
#define EDGE_BLOCKS ((N_TILES + WAVES*TPW_E - 1) / (WAVES*TPW_E))   // 1563

// CSR-build geometry
#define NB 128
#define CHUNK (N_EDGES / NB)     // 12500
#define NWORDS (N_NODES / 4)     // 12500 packed-u8 words

// scan geometry
#define SCAN_BS 256
#define SCAN_NB ((N_NODES + SCAN_BS - 1) / SCAN_BS)   // 196

// transpose scratch: 32 rows x 20 words (stride 20 => <=2-way banks, free)
#define TROW 20
#define TBUF (32 * TROW)

// xconv geometry
#define XCONV_BLOCKS ((N_NODES * 2 + 255) / 256)   // 391

// fused agg+node geometry: 16 nodes per block
#define AN_BLOCKS (N_NODES / 16)  // 3125
#define AROW 20

typedef short bf16x8 __attribute__((ext_vector_type(8)));
typedef float f32x4  __attribute__((ext_vector_type(4)));

__device__ inline unsigned pack_bf16(float a, float b) {
    __hip_bfloat162 p = __float22bfloat162_rn(float2{a, b});
    return *reinterpret_cast<unsigned*>(&p);
}

// ---------------- fused xconv + wprep (block-split)
__global__ __launch_bounds__(256) void xw_kernel(
    const float* __restrict__ x, unsigned short* __restrict__ xb,
    const float* __restrict__ W1, const float* __restrict__ b1,
    const float* __restrict__ W2, const float* __restrict__ b2,
    uint4* __restrict__ wtab,
    const float* __restrict__ oW1, const float* __restrict__ ob1,
    const float* __restrict__ oW2, const float* __restrict__ ob2,
    uint4* __restrict__ wtab2)
{
    if (blockIdx.x < XCONV_BLOCKS) {
        int i = blockIdx.x * 256 + threadIdx.x;
        if (i >= N_NODES * 2) return;
        const float4* xp = reinterpret_cast<const float4*>(x) + (size_t)i * 2;
        float4 a = xp[0], b = xp[1];
        uint4 o = make_uint4(pack_bf16(a.x, a.y), pack_bf16(a.z, a.w),
                             pack_bf16(b.x, b.y), pack_bf16(b.z, b.w));
        reinterpret_cast<uint4*>(xb)[i] = o;
        return;
    }
    if (threadIdx.x >= 64) return;
    const int lane = threadIdx.x;
    const int edge = lane & 15, kg = lane >> 4;
    // ---- fR table ----
#pragma unroll
    for (int t = 0; t < 4; ++t)
#pragma unroll
        for (int s = 0; s < 2; ++s) {
            union { uint4 q; unsigned u[4]; } fr;
#pragma unroll
            for (int r = 0; r < 4; ++r) {
                int k0 = s * 32 + kg * 8 + 2 * r;
                int n  = t * 16 + edge;
                float a = (k0 < M1) ? W1[k0 * HID + n] : (k0 == M1 ? b1[n] : 0.f);
                float b = (k0 + 1 < M1) ? W1[(k0 + 1) * HID + n] : 0.f;
                fr.u[r] = pack_bf16(a, b);
            }
            wtab[(t * 2 + s) * 64 + lane] = fr.q;
        }
#pragma unroll
    for (int s = 0; s < 2; ++s) {
        union { uint4 q; unsigned u[4]; } fr;
#pragma unroll
        for (int r = 0; r < 4; ++r) {
            int k0 = s * 32 + kg * 8 + 2 * r;
            fr.u[r] = pack_bf16(W2[k0 * ED + edge], W2[(k0 + 1) * ED + edge]);
        }
        wtab[(8 + s) * 64 + lane] = fr.q;
    }
    {
        float4 bb = make_float4(b2[kg * 4 + 0], b2[kg * 4 + 1],
                                b2[kg * 4 + 2], b2[kg * 4 + 3]);
        wtab[10 * 64 + lane] = *reinterpret_cast<uint4*>(&bb);
    }
    // ---- fO table ----
#pragma unroll
    for (int t = 0; t < 4; ++t) {
        union { uint4 q; unsigned u[4]; } fr;
#pragma unroll
        for (int r = 0; r < 4; ++r) {
            int k0 = kg * 8 + 2 * r;
            int n  = t * 16 + edge;
            fr.u[r] = pack_bf16(oW1[k0 * HID + n], oW1[(k0 + 1) * HID + n]);
        }
        wtab2[t * 64 + lane] = fr.q;
    }
#pragma unroll
    for (int s = 0; s < 2; ++s) {
        union { uint4 q; unsigned u[4]; } fr;
#pragma unroll
        for (int r = 0; r < 4; ++r) {
            int k0 = s * 32 + kg * 8 + 2 * r;
            fr.u[r] = pack_bf16(oW2[k0 * ED + edge], oW2[(k0 + 1) * ED + edge]);
        }
        wtab2[(4 + s) * 64 + lane] = fr.q;
    }
#pragma unroll
    for (int t = 0; t < 4; ++t) {
        float4 bb = make_float4(ob1[t * 16 + kg * 4 + 0], ob1[t * 16 + kg * 4 + 1],
                                ob1[t * 16 + kg * 4 + 2], ob1[t * 16 + kg * 4 + 3]);
        wtab2[(6 + t) * 64 + lane] = *reinterpret_cast<uint4*>(&bb);
    }
    {
        float4 bb = make_float4(ob2[kg * 4 + 0], ob2[kg * 4 + 1],
                                ob2[kg * 4 + 2], ob2[kg * 4 + 3]);
        wtab2[10 * 64 + lane] = *reinterpret_cast<uint4*>(&bb);
    }
}

// ---------------- fused edge MLP + hist (block-split, 256 threads, 50KB LDS)
// blocks [0,NB): single-pass LDS histogram; blocks [NB,..): edge MLP, depth-6 prefetch
__global__ __launch_bounds__(256) void edge_hist_kernel(
    const unsigned short* __restrict__ xb,  // [N,16] bf16
    const int* __restrict__ ei,
    const float* __restrict__ e,
    const uint4* __restrict__ wtab,
    float* __restrict__ e_new,
    unsigned* __restrict__ pw,              // [NB][NWORDS]
    unsigned char* __restrict__ slot8)      // [E]
{
    __shared__ __align__(16) unsigned ldsbuf[NWORDS];   // 50 KB

    if (blockIdx.x < NB) {
        const int b = blockIdx.x, t = threadIdx.x;
        for (int w = t; w < NWORDS; w += 256) ldsbuf[w] = 0u;
        __syncthreads();
        const int base = b * CHUNK;
        for (int i = t; i < CHUNK; i += 256) {
            int idx = base + i;
            int dst = ei[N_EDGES + idx];
            unsigned sh = (unsigned)(dst & 3) * 8u;
            unsigned old = atomicAdd(&ldsbuf[dst >> 2], 1u << sh);
            slot8[idx] = (unsigned char)((old >> sh) & 0xffu);
        }
        __syncthreads();
        unsigned* out = pw + (size_t)b * NWORDS;
        for (int w = t; w < NWORDS; w += 256) out[w] = ldsbuf[w];
        return;
    }

    // ======== edge MLP path ========
    const int lane = threadIdx.x & 63;
    const int wave = threadIdx.x >> 6;
    unsigned* T0 = ldsbuf + wave * 2 * TBUF;
    unsigned* T1 = T0 + TBUF;
    const int edge = lane & 15;
    const int kg   = lane >> 4;
    const bool lo32 = (kg < 2);
    const int h8 = kg & 1;

    bf16x8 w1f[4][2];
#pragma unroll
    for (int t = 0; t < 4; ++t)
#pragma unroll
        for (int s = 0; s < 2; ++s) {
            uint4 q = wtab[(t * 2 + s) * 64 + lane];
            w1f[t][s] = *reinterpret_cast<bf16x8*>(&q);
        }
    bf16x8 w2f[2];
#pragma unroll
    for (int s = 0; s < 2; ++s) {
        uint4 q = wtab[(8 + s) * 64 + lane];
        w2f[s] = *reinterpret_cast<bf16x8*>(&q);
    }
    float4 b2v;
    {
        uint4 q = wtab[10 * 64 + lane];
        b2v = *reinterpret_cast<float4*>(&q);
    }

    const int wtile0 = (((int)blockIdx.x - NB) * WAVES + wave) * TPW_E;
    if (wtile0 >= N_TILES) return;
    const int tmax = (wtile0 + TPW_E - 1 < N_TILES - 1) ? wtile0 + TPW_E - 1 : N_TILES - 1;

    const float4* e4 = reinterpret_cast<const float4*>(e);

    auto nid_of = [&](int tl) -> int {
        int tc = tl < tmax ? tl : tmax;
        return ei[(lo32 ? N_EDGES : 0) + tc * 16 + edge];
    };
    auto load_fx = [&](int nid) -> bf16x8 {
        return *reinterpret_cast<const bf16x8*>(xb + (size_t)nid * 16 + h8 * 8);
    };
    auto load_e2 = [&](int tl, float4& a, float4& b) {
        if (lo32) {
            int tc = tl < tmax ? tl : tmax;
            size_t o = (size_t)(tc * 16 + edge) * 4 + kg * 2;
            a = e4[o]; b = e4[o + 1];
        }
    };

    auto layer1 = [&](bf16x8 fx, const float4& ge0, const float4& ge1, unsigned* T) {
        union { bf16x8 v; unsigned u[4]; } fb;
        if (lo32) {
            fb.u[0] = pack_bf16(ge0.x, ge0.y); fb.u[1] = pack_bf16(ge0.z, ge0.w);
            fb.u[2] = pack_bf16(ge1.x, ge1.y); fb.u[3] = pack_bf16(ge1.z, ge1.w);
        } else {
            fb.u[0] = (kg == 2) ? 0x00003F80u : 0u;  // k=48 -> 1.0 (bias row)
            fb.u[1] = 0u; fb.u[2] = 0u; fb.u[3] = 0u;
        }
        const f32x4 z = {0.f, 0.f, 0.f, 0.f};
        f32x4 acc[4];
        __builtin_amdgcn_s_setprio(1);
#pragma unroll
        for (int tt = 0; tt < 4; ++tt) {
            acc[tt] = __builtin_amdgcn_mfma_f32_16x16x32_bf16(w1f[tt][0], fx, z, 0, 0, 0);
            acc[tt] = __builtin_amdgcn_mfma_f32_16x16x32_bf16(w1f[tt][1], fb.v, acc[tt], 0, 0, 0);
        }
        __builtin_amdgcn_s_setprio(0);
#pragma unroll
        for (int tt = 0; tt < 4; ++tt) {
            float h0 = fmaxf(acc[tt][0], 0.f);
            float h1 = fmaxf(acc[tt][1], 0.f);
            float h2 = fmaxf(acc[tt][2], 0.f);
            float h3 = fmaxf(acc[tt][3], 0.f);
            T[(8 * tt + 2 * kg + 0) * TROW + edge] = pack_bf16(h0, h1);
            T[(8 * tt + 2 * kg + 1) * TROW + edge] = pack_bf16(h2, h3);
        }
    };

    auto layer2 = [&](int tile, const unsigned* T) {
        union { bf16x8 v; unsigned u[4]; } hf0, hf1;
#pragma unroll
        for (int j = 0; j < 4; ++j) {
            hf0.u[j] = T[(kg * 4 + j) * TROW + edge];
            hf1.u[j] = T[(16 + kg * 4 + j) * TROW + edge];
        }
        const f32x4 z = {0.f, 0.f, 0.f, 0.f};
        f32x4 o = __builtin_amdgcn_mfma_f32_16x16x32_bf16(w2f[0], hf0.v, z, 0, 0, 0);
        o = __builtin_amdgcn_mfma_f32_16x16x32_bf16(w2f[1], hf1.v, o, 0, 0, 0);
        if (tile < N_TILES) {
            float4 st = make_float4(o[0] + b2v.x, o[1] + b2v.y,
                                    o[2] + b2v.z, o[3] + b2v.w);
            *reinterpret_cast<float4*>(e_new + (size_t)(tile * 16 + edge) * 16 + kg * 4) = st;
        }
    };

    // ---- depth-6 software pipeline; fully unrolled -> all slot indices static ----
    const int t0 = wtile0;
    int    nid8[8];
    bf16x8 fx8[8];
    float4 ge0a[8], ge1a[8];

    // prologue: nids + loads for tiles 0..5
#pragma unroll
    for (int u = 0; u < 6; ++u) nid8[u & 7] = nid_of(t0 + u);
#pragma unroll
    for (int u = 0; u < 6; ++u) {
        fx8[u & 7] = load_fx(nid8[u & 7]);
        load_e2(t0 + u, ge0a[u & 7], ge1a[u & 7]);
    }
    // nids for tiles 6..13
#pragma unroll
    for (int u = 6; u < 14; ++u) nid8[u & 7] = nid_of(t0 + u);

#pragma unroll
    for (int s = 0; s < TPW_E; ++s) {
        layer1(fx8[s & 7], ge0a[s & 7], ge1a[s & 7], (s & 1) ? T1 : T0);
        // prefetch loads for tile s+6 (clamped by helpers beyond tmax)
        fx8[(s + 6) & 7] = load_fx(nid8[(s + 6) & 7]);
        load_e2(t0 + s + 6, ge0a[(s + 6) & 7], ge1a[(s + 6) & 7]);
        // prefetch nid for tile s+14 (slot just freed this step)
        nid8[(s + 14) & 7] = nid_of(t0 + s + 14);
        if (s > 0) layer2(t0 + s - 1, (s & 1) ? T0 : T1);
    }
    layer2(t0 + TPW_E - 1, (TPW_E & 1) ? T0 : T1);
}

// ---------------- bprefix: one WAVE per word; packed-u8 shfl scan over 128 blocks
__global__ __launch_bounds__(256) void bprefix_kernel(
    unsigned* __restrict__ pw, unsigned* __restrict__ count)
{
    int word = blockIdx.x * 4 + (threadIdx.x >> 6);
    if (word >= NWORDS) return;
    int lane = threadIdx.x & 63;
    size_t o0 = (size_t)(2 * lane) * NWORDS + word;
    size_t o1 = (size_t)(2 * lane + 1) * NWORDS + word;
    unsigned v0 = pw[o0], v1 = pw[o1];
    unsigned s = v0 + v1;
    unsigned t = s;
#pragma unroll
    for (int d = 1; d < 64; d <<= 1) {
        unsigned u = __shfl_up(t, d, 64);
        if (lane >= d) t += u;
    }
    unsigned excl = t - s;
    pw[o0] = excl;
    pw[o1] = excl + v0;
    if (lane == 63) {
        unsigned tot = t;
        count[word * 4 + 0] = tot & 0xffu;
        count[word * 4 + 1] = (tot >> 8) & 0xffu;
        count[word * 4 + 2] = (tot >> 16) & 0xffu;
        count[word * 4 + 3] = (tot >> 24) & 0xffu;
    }
}

// ---------------- 3-phase parallel scan: count[N] -> offs[N+1]
__global__ __launch_bounds__(SCAN_BS) void scan_blocks_kernel(
    const unsigned* __restrict__ count, unsigned* __restrict__ offs,
    unsigned* __restrict__ bsum)
{
    __shared__ unsigned s[SCAN_BS];
    const int b = blockIdx.x, t = threadIdx.x;
    const int n = b * SCAN_BS + t;
    unsigned v = (n < N_NODES) ? count[n] : 0u;
    s[t] = v;
    __syncthreads();
    for (int d = 1; d < SCAN_BS; d <<= 1) {
        unsigned u = (t >= d) ? s[t - d] : 0u;
        __syncthreads();
        s[t] += u;
        __syncthreads();
    }
    if (n < N_NODES) offs[n] = s[t] - v;
    if (t == SCAN_BS - 1) bsum[b] = s[t];
}

__global__ __launch_bounds__(256) void scan_bsum_kernel(
    const unsigned* __restrict__ bsum, unsigned* __restrict__ bbase,
    unsigned* __restrict__ offs)
{
    __shared__ unsigned s[256];
    const int t = threadIdx.x;
    unsigned v = (t < SCAN_NB) ? bsum[t] : 0u;
    s[t] = v;
    __syncthreads();
    for (int d = 1; d < 256; d <<= 1) {
        unsigned u = (t >= d) ? s[t - d] : 0u;
        __syncthreads();
        s[t] += u;
        __syncthreads();
    }
    if (t < SCAN_NB) bbase[t] = s[t] - v;
    if (t == SCAN_NB - 1) offs[N_NODES] = s[t];
}

__global__ __launch_bounds__(SCAN_BS) void scan_add_kernel(
    unsigned* __restrict__ offs, const unsigned* __restrict__ bbase)
{
    const int n = blockIdx.x * SCAN_BS + threadIdx.x;
    if (n < N_NODES) offs[n] += bbase[blockIdx.x];
}

// ---------------- fill2: elist[offs[dst] + bp[b][dst] + slot8[idx]] = idx
__global__ __launch_bounds__(1024) void fill2_kernel(
    const int* __restrict__ ei, const unsigned* __restrict__ offs,
    const unsigned* __restrict__ bp_w,
    const unsigned char* __restrict__ slot8,
    unsigned* __restrict__ elist)
{
    const int b = blockIdx.x, t = threadIdx.x;
    const int base = b * CHUNK;
    const unsigned* bpb = bp_w + (size_t)b * NWORDS;
    for (int i = t; i < CHUNK; i += 1024) {
        int idx = base + i;
        int dst = ei[N_EDGES + idx];
        unsigned pre = (bpb[dst >> 2] >> ((unsigned)(dst & 3) * 8u)) & 0xffu;
        unsigned pos = offs[dst] + pre + (unsigned)slot8[idx];
        elist[pos] = (unsigned)idx;
    }
}

// ---------------- fused agg + node MLP: 3125 blocks x 16 nodes
__global__ __launch_bounds__(256) void agg_node16_kernel(
    const float* __restrict__ e_new, const unsigned* __restrict__ offs,
    const unsigned* __restrict__ elist, const float* __restrict__ x,
    const uint4* __restrict__ wtab2, float* __restrict__ x_new)
{
    __shared__ float aggl[16 * AROW];       // 1.25 KB
    __shared__ unsigned Tl[TBUF];           // 2.5 KB
    const int node0 = blockIdx.x * 16;
    const int tid = threadIdx.x;

    uint4 wq0, wq1, wq2, wq3, wq4, wq5, wq6, wq7, wq8, wq9, wq10;
    if (tid < 64) {
        wq0 = wtab2[0 * 64 + tid]; wq1 = wtab2[1 * 64 + tid];
        wq2 = wtab2[2 * 64 + tid]; wq3 = wtab2[3 * 64 + tid];
        wq4 = wtab2[4 * 64 + tid]; wq5 = wtab2[5 * 64 + tid];
        wq6 = wtab2[6 * 64 + tid]; wq7 = wtab2[7 * 64 + tid];
        wq8 = wtab2[8 * 64 + tid]; wq9 = wtab2[9 * 64 + tid];
        wq10 = wtab2[10 * 64 + tid];
    }

    {
        const int nl = tid >> 4;
        const int q  = tid & 3;
        const int r  = (tid >> 2) & 3;
        const int n  = node0 + nl;
        unsigned lo = offs[n], hi = offs[n + 1];
        const float4* ep = reinterpret_cast<const float4*>(e_new);
        float sx = 0.f, sy = 0.f, sz = 0.f, sw = 0.f;
        unsigned j = lo + r;
        unsigned eid = (j < hi) ? elist[j] : 0u;
        while (j < hi) {
            unsigned cur = eid;
            unsigned jn = j + 4;
            if (jn < hi) eid = elist[jn];
            float4 v = ep[(size_t)cur * 4 + q];
            sx += v.x; sy += v.y; sz += v.z; sw += v.w;
            j = jn;
        }
        sx += __shfl_xor(sx, 4, 64); sy += __shfl_xor(sy, 4, 64);
        sz += __shfl_xor(sz, 4, 64); sw += __shfl_xor(sw, 4, 64);
        sx += __shfl_xor(sx, 8, 64); sy += __shfl_xor(sy, 8, 64);
        sz += __shfl_xor(sz, 8, 64); sw += __shfl_xor(sw, 8, 64);
        if (r == 0)
            *reinterpret_cast<float4*>(aggl + nl * AROW + q * 4) =
                make_float4(sx, sy, sz, sw);
    }
    __syncthreads();
    if (tid >= 64) return;

    const int lane = tid;
    const int nd = lane & 15;
    const int kg = lane >> 4;
    const bool lo32 = (kg < 2);
    const int h8 = kg & 1;

    bf16x8 w1f0 = *reinterpret_cast<bf16x8*>(&wq0);
    bf16x8 w1f1 = *reinterpret_cast<bf16x8*>(&wq1);
    bf16x8 w1f2 = *reinterpret_cast<bf16x8*>(&wq2);
    bf16x8 w1f3 = *reinterpret_cast<bf16x8*>(&wq3);
    bf16x8 w2f0 = *reinterpret_cast<bf16x8*>(&wq4);
    bf16x8 w2f1 = *reinterpret_cast<bf16x8*>(&wq5);
    float4 b1v0 = *reinterpret_cast<float4*>(&wq6);
    float4 b1v1 = *reinterpret_cast<float4*>(&wq7);
    float4 b1v2 = *reinterpret_cast<float4*>(&wq8);
    float4 b1v3 = *reinterpret_cast<float4*>(&wq9);
    float4 b2v  = *reinterpret_cast<float4*>(&wq10);

    const int node = node0 + nd;
    float4 g0, g1;
    if (lo32) {
        const float4* x4 = reinterpret_cast<const float4*>(x);
        size_t o = (size_t)node * 4 + h8 * 2;
        g0 = x4[o]; g1 = x4[o + 1];
    } else {
        g0 = *reinterpret_cast<float4*>(aggl + nd * AROW + h8 * 8);
        g1 = *reinterpret_cast<float4*>(aggl + nd * AROW + h8 * 8 + 4);
    }

    union { bf16x8 v; unsigned u[4]; } fa;
    fa.u[0] = pack_bf16(g0.x, g0.y); fa.u[1] = pack_bf16(g0.z, g0.w);
    fa.u[2] = pack_bf16(g1.x, g1.y); fa.u[3] = pack_bf16(g1.z, g1.w);

    const f32x4 z = {0.f, 0.f, 0.f, 0.f};
    f32x4 acc0 = __builtin_amdgcn_mfma_f32_16x16x32_bf16(w1f0, fa.v, z, 0, 0, 0);
    f32x4 acc1 = __builtin_amdgcn_mfma_f32_16x16x32_bf16(w1f1, fa.v, z, 0, 0, 0);
    f32x4 acc2 = __builtin_amdgcn_mfma_f32_16x16x32_bf16(w1f2, fa.v, z, 0, 0, 0);
    f32x4 acc3 = __builtin_amdgcn_mfma_f32_16x16x32_bf16(w1f3, fa.v, z, 0, 0, 0);

    {
        float h0 = fmaxf(acc0[0] + b1v0.x, 0.f), h1 = fmaxf(acc0[1] + b1v0.y, 0.f);
        float h2 = fmaxf(acc0[2] + b1v0.z, 0.f), h3 = fmaxf(acc0[3] + b1v0.w, 0.f);
        Tl[(0 + 2 * kg + 0) * TROW + nd] = pack_bf16(h0, h1);
        Tl[(0 + 2 * kg + 1) * TROW + nd] = pack_bf16(h2, h3);
        h0 = fmaxf(acc1[0] + b1v1.x, 0.f); h1 = fmaxf(acc1[1] + b1v1.y, 0.f);
        h2 = fmaxf(acc1[2] + b1v1.z, 0.f); h3 = fmaxf(acc1[3] + b1v1.w, 0.f);
        Tl[(8 + 2 * kg + 0) * TROW + nd] = pack_bf16(h0, h1);
        Tl[(8 + 2 * kg + 1) * TROW + nd] = pack_bf16(h2, h3);
        h0 = fmaxf(acc2[0] + b1v2.x, 0.f); h1 = fmaxf(acc2[1] + b1v2.y, 0.f);
        h2 = fmaxf(acc2[2] + b1v2.z, 0.f); h3 = fmaxf(acc2[3] + b1v2.w, 0.f);
        Tl[(16 + 2 * kg + 0) * TROW + nd] = pack_bf16(h0, h1);
        Tl[(16 + 2 * kg + 1) * TROW + nd] = pack_bf16(h2, h3);
        h0 = fmaxf(acc3[0] + b1v3.x, 0.f); h1 = fmaxf(acc3[1] + b1v3.y, 0.f);
        h2 = fmaxf(acc3[2] + b1v3.z, 0.f); h3 = fmaxf(acc3[3] + b1v3.w, 0.f);
        Tl[(24 + 2 * kg + 0) * TROW + nd] = pack_bf16(h0, h1);
        Tl[(24 + 2 * kg + 1) * TROW + nd] = pack_bf16(h2, h3);
    }

    union { bf16x8 v; unsigned u[4]; } hf0, hf1;
#pragma unroll
    for (int j = 0; j < 4; ++j) {
        hf0.u[j] = Tl[(kg * 4 + j) * TROW + nd];
        hf1.u[j] = Tl[(16 + kg * 4 + j) * TROW + nd];
    }
    f32x4 oo = __builtin_amdgcn_mfma_f32_16x16x32_bf16(w2f0, hf0.v, z, 0, 0, 0);
    oo = __builtin_amdgcn_mfma_f32_16x16x32_bf16(w2f1, hf1.v, oo, 0, 0, 0);

    float4 st = make_float4(oo[0] + b2v.x, oo[1] + b2v.y,
                            oo[2] + b2v.z, oo[3] + b2v.w);
    *reinterpret_cast<float4*>(x_new + (size_t)node * 16 + kg * 4) = st;
}

// ---------------- legacy fallback kernels (ws too small)
__global__ __launch_bounds__(256) void edge_kernel_atomic(
    const float* __restrict__ x, const int* __restrict__ ei,
    const float* __restrict__ e,
    const float* __restrict__ W1, const float* __restrict__ b1,
    const float* __restrict__ W2, const float* __restrict__ b2,
    float* __restrict__ e_new, float* __restrict__ agg)
{
    int idx = blockIdx.x * blockDim.x + threadIdx.x;
    if (idx >= N_EDGES) return;
    int src = ei[idx];
    int dst = ei[N_EDGES + idx];
    float m[M1];
    const float4* xd = reinterpret_cast<const float4*>(x) + dst * 4;
    const float4* xs = reinterpret_cast<const float4*>(x) + src * 4;
    const float4* ep = reinterpret_cast<const float4*>(e) + (size_t)idx * 4;
#pragma unroll
    for (int q = 0; q < 4; ++q) { float4 v = xd[q]; m[4*q]=v.x; m[4*q+1]=v.y; m[4*q+2]=v.z; m[4*q+3]=v.w; }
#pragma unroll
    for (int q = 0; q < 4; ++q) { float4 v = xs[q]; m[16+4*q]=v.x; m[16+4*q+1]=v.y; m[16+4*q+2]=v.z; m[16+4*q+3]=v.w; }
#pragma unroll
    for (int q = 0; q < 4; ++q) { float4 v = ep[q]; m[32+4*q]=v.x; m[32+4*q+1]=v.y; m[32+4*q+2]=v.z; m[32+4*q+3]=v.w; }
    float h[HID];
#pragma unroll
    for (int j = 0; j < HID; ++j) h[j] = b1[j];
#pragma unroll 4
    for (int i = 0; i < M1; ++i) {
        float mi = m[i]; const float* wr = W1 + i * HID;
#pragma unroll
        for (int j = 0; j < HID; ++j) h[j] = fmaf(mi, wr[j], h[j]);
    }
    float o[ED];
#pragma unroll
    for (int k = 0; k < ED; ++k) o[k] = b2[k];
#pragma unroll 8
    for (int j = 0; j < HID; ++j) {
        float hj = fmaxf(h[j], 0.0f); const float* wr = W2 + j * ED;
#pragma unroll
        for (int k = 0; k < ED; ++k) o[k] = fmaf(hj, wr[k], o[k]);
    }
    float4* op = reinterpret_cast<float4*>(e_new) + (size_t)idx * 4;
    op[0] = make_float4(o[0],o[1],o[2],o[3]);
    op[1] = make_float4(o[4],o[5],o[6],o[7]);
    op[2] = make_float4(o[8],o[9],o[10],o[11]);
    op[3] = make_float4(o[12],o[13],o[14],o[15]);
    float* ag = agg + (size_t)dst * ED;
#pragma unroll
    for (int k = 0; k < ED; ++k) atomicAdd(ag + k, o[k]);
}

__global__ __launch_bounds__(256) void node_kernel(
    const float* __restrict__ x, const float* __restrict__ agg,
    const float* __restrict__ W1, const float* __restrict__ b1,
    const float* __restrict__ W2, const float* __restrict__ b2,
    float* __restrict__ x_new)
{
    int idx = blockIdx.x * blockDim.x + threadIdx.x;
    if (idx >= N_NODES) return;
    float m[M2];
    const float4* xp = reinterpret_cast<const float4*>(x) + idx * 4;
    const float4* ap = reinterpret_cast<const float4*>(agg) + idx * 4;
#pragma unroll
    for (int q = 0; q < 4; ++q) { float4 v = xp[q]; m[4*q]=v.x; m[4*q+1]=v.y; m[4*q+2]=v.z; m[4*q+3]=v.w; }
#pragma unroll
    for (int q = 0; q < 4; ++q) { float4 v = ap[q]; m[16+4*q]=v.x; m[16+4*q+1]=v.y; m[16+4*q+2]=v.z; m[16+4*q+3]=v.w; }
    float h[HID];
#pragma unroll
    for (int j = 0; j < HID; ++j) h[j] = b1[j];
#pragma unroll 4
    for (int i = 0; i < M2; ++i) {
        float mi = m[i]; const float* wr = W1 + i * HID;
#pragma unroll
        for (int j = 0; j < HID; ++j) h[j] = fmaf(mi, wr[j], h[j]);
    }
    float o[ED];
#pragma unroll
    for (int k = 0; k < ED; ++k) o[k] = b2[k];
#pragma unroll 8
    for (int j = 0; j < HID; ++j) {
        float hj = fmaxf(h[j], 0.0f); const float* wr = W2 + j * ED;
#pragma unroll
        for (int k = 0; k < ED; ++k) o[k] = fmaf(hj, wr[k], o[k]);
    }
    float4* op = reinterpret_cast<float4*>(x_new) + idx * 4;
    op[0] = make_float4(o[0],o[1],o[2],o[3]);
    op[1] = make_float4(o[4],o[5],o[6],o[7]);
    op[2] = make_float4(o[8],o[9],o[10],o[11]);
    op[3] = make_float4(o[12],o[13],o[14],o[15]);
}

static inline size_t align_up(size_t v, size_t a) { return (v + a - 1) / a * a; }

extern "C" void kernel_launch(void* const* d_in, const int* in_sizes, int n_in,
                              void* d_out, int out_size, void* d_ws, size_t ws_size,
                              hipStream_t stream) {
    const float* x     = (const float*)d_in[0];
    const int*   ei    = (const int*)  d_in[1];
    const float* e     = (const float*)d_in[2];
    const float* fR_W1 = (const float*)d_in[3];
    const float* fR_b1 = (const float*)d_in[4];
    const float* fR_W2 = (const float*)d_in[5];
    const float* fR_b2 = (const float*)d_in[6];
    const float* fO_W1 = (const float*)d_in[7];
    const float* fO_b1 = (const float*)d_in[8];
    const float* fO_W2 = (const float*)d_in[9];
    const float* fO_b2 = (const float*)d_in[10];

    float* x_new = (float*)d_out;                        // [N, 16]
    float* e_new = (float*)d_out + (size_t)N_NODES * ND; // [E, 16]

    char* ws = (char*)d_ws;
    size_t o = 0;
    unsigned*       offs  = (unsigned*)(ws + o);       o += align_up((size_t)(N_NODES + 1) * 4, 256);
    unsigned*       count = (unsigned*)(ws + o);       o += align_up((size_t)N_NODES * 4, 256);
    unsigned char*  slot8 = (unsigned char*)(ws + o);  o += align_up((size_t)N_EDGES, 256);
    unsigned*       pw    = (unsigned*)(ws + o);       o += align_up((size_t)NB * NWORDS * 4, 256);
    unsigned*       elist = (unsigned*)(ws + o);       o += align_up((size_t)N_EDGES * 4, 256);
    unsigned*       bsum  = (unsigned*)(ws + o);       o += align_up((size_t)SCAN_NB * 4, 256);
    unsigned*       bbase = (unsigned*)(ws + o);       o += align_up((size_t)SCAN_NB * 4, 256);
    unsigned short* xb    = (unsigned short*)(ws + o); o += align_up((size_t)N_NODES * ND * 2, 256);
    uint4*          wtab  = (uint4*)(ws + o);          o += align_up((size_t)11 * 64 * 16, 256);
    uint4*          wtab2 = (uint4*)(ws + o);          o += align_up((size_t)11 * 64 * 16, 256);
    const size_t need = o;   // ~16.4 MB

    if (ws_size >= need) {
        xw_kernel<<<XCONV_BLOCKS + 1, 256, 0, stream>>>(
            x, xb, fR_W1, fR_b1, fR_W2, fR_b2, wtab,
            fO_W1, fO_b1, fO_W2, fO_b2, wtab2);

        // fused: 128 hist blocks + 1563 edge blocks (50 KB LDS each)
        edge_hist_kernel<<<NB + EDGE_BLOCKS, 256, 0, stream>>>(
            xb, ei, e, wtab, e_new, pw, slot8);

        bprefix_kernel<<<(NWORDS + 3) / 4, 256, 0, stream>>>(pw, count);
        scan_blocks_kernel<<<SCAN_NB, SCAN_BS, 0, stream>>>(count, offs, bsum);
        scan_bsum_kernel<<<1, 256, 0, stream>>>(bsum, bbase, offs);
        scan_add_kernel<<<SCAN_NB, SCAN_BS, 0, stream>>>(offs, bbase);
        fill2_kernel<<<NB, 1024, 0, stream>>>(ei, offs, pw, slot8, elist);

        agg_node16_kernel<<<AN_BLOCKS, 256, 0, stream>>>(
            e_new, offs, elist, x, wtab2, x_new);
    } else {
        float* agg0 = (float*)d_ws;
        hipMemsetAsync(agg0, 0, (size_t)N_NODES * ED * 4, stream);
        edge_kernel_atomic<<<N_EDGES / 256, 256, 0, stream>>>(
            x, ei, e, fR_W1, fR_b1, fR_W2, fR_b2, e_new, agg0);
        node_kernel<<<(N_NODES + 255) / 256, 256, 0, stream>>>(
            x, agg0, fO_W1, fO_b1, fO_W2, fO_b2, x_new);
    }
}

// Round 18
// 164.914 us; speedup vs baseline: 1.1154x; 1.1154x over previous
//
#include <hip/hip_runtime.h>
#include <hip/hip_bf16.h>

#define N_NODES 50000
#define N_EDGES 1600000
#define ND 16
#define ED 16
#define HID 64
#define M1 (2*ND+ED)   // 48
#define M2 (ND+ED)     // 32
#define N_TILES (N_EDGES / 16)   // 100000
#define WAVES 4
#define TPW_E 16                  // tiles per wave (edge)
#define EDGE_BLOCKS ((N_TILES + WAVES*TPW_E - 1) / (WAVES*TPW_E))   // 1563

// CSR-build geometry
#define NB 128
#define CHUNK (N_EDGES / NB)     // 12500
#define NWORDS (N_NODES / 4)     // 12500 packed-u8 words

// scan geometry
#define SCAN_BS 256
#define SCAN_NB ((N_NODES + SCAN_BS - 1) / SCAN_BS)   // 196

// transpose scratch: 32 rows x 20 words (stride 20 => <=2-way banks, free)
#define TROW 20
#define TBUF (32 * TROW)

// xconv geometry
#define XCONV_BLOCKS ((N_NODES * 2 + 255) / 256)   // 391

// fused agg+node geometry: 16 nodes per block
#define AN_BLOCKS (N_NODES / 16)  // 3125
#define AROW 20

typedef short bf16x8 __attribute__((ext_vector_type(8)));
typedef float f32x4  __attribute__((ext_vector_type(4)));

__device__ inline unsigned pack_bf16(float a, float b) {
    __hip_bfloat162 p = __float22bfloat162_rn(float2{a, b});
    return *reinterpret_cast<unsigned*>(&p);
}

// ---------------- fused xconv + wprep (block-split)
__global__ __launch_bounds__(256) void xw_kernel(
    const float* __restrict__ x, unsigned short* __restrict__ xb,
    const float* __restrict__ W1, const float* __restrict__ b1,
    const float* __restrict__ W2, const float* __restrict__ b2,
    uint4* __restrict__ wtab,
    const float* __restrict__ oW1, const float* __restrict__ ob1,
    const float* __restrict__ oW2, const float* __restrict__ ob2,
    uint4* __restrict__ wtab2)
{
    if (blockIdx.x < XCONV_BLOCKS) {
        int i = blockIdx.x * 256 + threadIdx.x;
        if (i >= N_NODES * 2) return;
        const float4* xp = reinterpret_cast<const float4*>(x) + (size_t)i * 2;
        float4 a = xp[0], b = xp[1];
        uint4 o = make_uint4(pack_bf16(a.x, a.y), pack_bf16(a.z, a.w),
                             pack_bf16(b.x, b.y), pack_bf16(b.z, b.w));
        reinterpret_cast<uint4*>(xb)[i] = o;
        return;
    }
    if (threadIdx.x >= 64) return;
    const int lane = threadIdx.x;
    const int edge = lane & 15, kg = lane >> 4;
    // ---- fR table ----
#pragma unroll
    for (int t = 0; t < 4; ++t)
#pragma unroll
        for (int s = 0; s < 2; ++s) {
            union { uint4 q; unsigned u[4]; } fr;
#pragma unroll
            for (int r = 0; r < 4; ++r) {
                int k0 = s * 32 + kg * 8 + 2 * r;
                int n  = t * 16 + edge;
                float a = (k0 < M1) ? W1[k0 * HID + n] : (k0 == M1 ? b1[n] : 0.f);
                float b = (k0 + 1 < M1) ? W1[(k0 + 1) * HID + n] : 0.f;
                fr.u[r] = pack_bf16(a, b);
            }
            wtab[(t * 2 + s) * 64 + lane] = fr.q;
        }
#pragma unroll
    for (int s = 0; s < 2; ++s) {
        union { uint4 q; unsigned u[4]; } fr;
#pragma unroll
        for (int r = 0; r < 4; ++r) {
            int k0 = s * 32 + kg * 8 + 2 * r;
            fr.u[r] = pack_bf16(W2[k0 * ED + edge], W2[(k0 + 1) * ED + edge]);
        }
        wtab[(8 + s) * 64 + lane] = fr.q;
    }
    {
        float4 bb = make_float4(b2[kg * 4 + 0], b2[kg * 4 + 1],
                                b2[kg * 4 + 2], b2[kg * 4 + 3]);
        wtab[10 * 64 + lane] = *reinterpret_cast<uint4*>(&bb);
    }
    // ---- fO table ----
#pragma unroll
    for (int t = 0; t < 4; ++t) {
        union { uint4 q; unsigned u[4]; } fr;
#pragma unroll
        for (int r = 0; r < 4; ++r) {
            int k0 = kg * 8 + 2 * r;
            int n  = t * 16 + edge;
            fr.u[r] = pack_bf16(oW1[k0 * HID + n], oW1[(k0 + 1) * HID + n]);
        }
        wtab2[t * 64 + lane] = fr.q;
    }
#pragma unroll
    for (int s = 0; s < 2; ++s) {
        union { uint4 q; unsigned u[4]; } fr;
#pragma unroll
        for (int r = 0; r < 4; ++r) {
            int k0 = s * 32 + kg * 8 + 2 * r;
            fr.u[r] = pack_bf16(oW2[k0 * ED + edge], oW2[(k0 + 1) * ED + edge]);
        }
        wtab2[(4 + s) * 64 + lane] = fr.q;
    }
#pragma unroll
    for (int t = 0; t < 4; ++t) {
        float4 bb = make_float4(ob1[t * 16 + kg * 4 + 0], ob1[t * 16 + kg * 4 + 1],
                                ob1[t * 16 + kg * 4 + 2], ob1[t * 16 + kg * 4 + 3]);
        wtab2[(6 + t) * 64 + lane] = *reinterpret_cast<uint4*>(&bb);
    }
    {
        float4 bb = make_float4(ob2[kg * 4 + 0], ob2[kg * 4 + 1],
                                ob2[kg * 4 + 2], ob2[kg * 4 + 3]);
        wtab2[10 * 64 + lane] = *reinterpret_cast<uint4*>(&bb);
    }
}

// ---------------- fused edge MLP + hist (block-split, 256 threads, 50KB LDS)
// blocks [0,NB): single-pass LDS histogram (u8 x4 packed) + local slot
// blocks [NB, NB+EDGE_BLOCKS): MFMA edge MLP (uses first 20KB of LDS)
__global__ __launch_bounds__(256) void edge_hist_kernel(
    const unsigned short* __restrict__ xb,  // [N,16] bf16
    const int* __restrict__ ei,
    const float* __restrict__ e,
    const uint4* __restrict__ wtab,
    float* __restrict__ e_new,
    unsigned* __restrict__ pw,              // [NB][NWORDS]
    unsigned char* __restrict__ slot8)      // [E]
{
    __shared__ __align__(16) unsigned ldsbuf[NWORDS];   // 50 KB

    if (blockIdx.x < NB) {
        // ======== hist path: single pass, 256 threads ========
        const int b = blockIdx.x, t = threadIdx.x;
        for (int w = t; w < NWORDS; w += 256) ldsbuf[w] = 0u;
        __syncthreads();
        const int base = b * CHUNK;
        for (int i = t; i < CHUNK; i += 256) {
            int idx = base + i;
            int dst = ei[N_EDGES + idx];
            unsigned sh = (unsigned)(dst & 3) * 8u;
            unsigned old = atomicAdd(&ldsbuf[dst >> 2], 1u << sh);
            slot8[idx] = (unsigned char)((old >> sh) & 0xffu);
        }
        __syncthreads();
        unsigned* out = pw + (size_t)b * NWORDS;
        for (int w = t; w < NWORDS; w += 256) out[w] = ldsbuf[w];
        return;
    }

    // ======== edge MLP path ========
    const int lane = threadIdx.x & 63;
    const int wave = threadIdx.x >> 6;
    unsigned* T0 = ldsbuf + wave * 2 * TBUF;
    unsigned* T1 = T0 + TBUF;
    const int edge = lane & 15;
    const int kg   = lane >> 4;
    const bool lo32 = (kg < 2);
    const int h8 = kg & 1;

    bf16x8 w1f[4][2];
#pragma unroll
    for (int t = 0; t < 4; ++t)
#pragma unroll
        for (int s = 0; s < 2; ++s) {
            uint4 q = wtab[(t * 2 + s) * 64 + lane];
            w1f[t][s] = *reinterpret_cast<bf16x8*>(&q);
        }
    bf16x8 w2f[2];
#pragma unroll
    for (int s = 0; s < 2; ++s) {
        uint4 q = wtab[(8 + s) * 64 + lane];
        w2f[s] = *reinterpret_cast<bf16x8*>(&q);
    }
    float4 b2v;
    {
        uint4 q = wtab[10 * 64 + lane];
        b2v = *reinterpret_cast<float4*>(&q);
    }

    const int wtile0 = (((int)blockIdx.x - NB) * WAVES + wave) * TPW_E;
    if (wtile0 >= N_TILES) return;
    const int tmax = (wtile0 + TPW_E - 1 < N_TILES - 1) ? wtile0 + TPW_E - 1 : N_TILES - 1;

    const float4* e4 = reinterpret_cast<const float4*>(e);

    auto nid_of = [&](int tl) -> int {
        int tc = tl < tmax ? tl : tmax;
        return ei[(lo32 ? N_EDGES : 0) + tc * 16 + edge];
    };
    auto load_fx = [&](int nid) -> bf16x8 {
        return *reinterpret_cast<const bf16x8*>(xb + (size_t)nid * 16 + h8 * 8);
    };
    auto load_e2 = [&](int tl, float4& a, float4& b) {
        if (lo32) {
            int tc = tl < tmax ? tl : tmax;
            size_t o = (size_t)(tc * 16 + edge) * 4 + kg * 2;
            a = e4[o]; b = e4[o + 1];
        }
    };

    auto layer1 = [&](bf16x8 fx, const float4& ge0, const float4& ge1, unsigned* T) {
        union { bf16x8 v; unsigned u[4]; } fb;
        if (lo32) {
            fb.u[0] = pack_bf16(ge0.x, ge0.y); fb.u[1] = pack_bf16(ge0.z, ge0.w);
            fb.u[2] = pack_bf16(ge1.x, ge1.y); fb.u[3] = pack_bf16(ge1.z, ge1.w);
        } else {
            fb.u[0] = (kg == 2) ? 0x00003F80u : 0u;  // k=48 -> 1.0 (bias row)
            fb.u[1] = 0u; fb.u[2] = 0u; fb.u[3] = 0u;
        }
        const f32x4 z = {0.f, 0.f, 0.f, 0.f};
        f32x4 acc[4];
        __builtin_amdgcn_s_setprio(1);
#pragma unroll
        for (int tt = 0; tt < 4; ++tt) {
            acc[tt] = __builtin_amdgcn_mfma_f32_16x16x32_bf16(w1f[tt][0], fx, z, 0, 0, 0);
            acc[tt] = __builtin_amdgcn_mfma_f32_16x16x32_bf16(w1f[tt][1], fb.v, acc[tt], 0, 0, 0);
        }
        __builtin_amdgcn_s_setprio(0);
#pragma unroll
        for (int tt = 0; tt < 4; ++tt) {
            float h0 = fmaxf(acc[tt][0], 0.f);
            float h1 = fmaxf(acc[tt][1], 0.f);
            float h2 = fmaxf(acc[tt][2], 0.f);
            float h3 = fmaxf(acc[tt][3], 0.f);
            T[(8 * tt + 2 * kg + 0) * TROW + edge] = pack_bf16(h0, h1);
            T[(8 * tt + 2 * kg + 1) * TROW + edge] = pack_bf16(h2, h3);
        }
    };

    auto layer2 = [&](int tile, const unsigned* T) {
        union { bf16x8 v; unsigned u[4]; } hf0, hf1;
#pragma unroll
        for (int j = 0; j < 4; ++j) {
            hf0.u[j] = T[(kg * 4 + j) * TROW + edge];
            hf1.u[j] = T[(16 + kg * 4 + j) * TROW + edge];
        }
        const f32x4 z = {0.f, 0.f, 0.f, 0.f};
        f32x4 o = __builtin_amdgcn_mfma_f32_16x16x32_bf16(w2f[0], hf0.v, z, 0, 0, 0);
        o = __builtin_amdgcn_mfma_f32_16x16x32_bf16(w2f[1], hf1.v, o, 0, 0, 0);
        if (tile < N_TILES) {
            float4 st = make_float4(o[0] + b2v.x, o[1] + b2v.y,
                                    o[2] + b2v.z, o[3] + b2v.w);
            *reinterpret_cast<float4*>(e_new + (size_t)(tile * 16 + edge) * 16 + kg * 4) = st;
        }
    };

    bf16x8 fxA, fxB, fxC, fxD;
    float4 geA0, geA1, geB0, geB1, geC0, geC1, geD0, geD1;

    const int t0 = wtile0;
    int m0 = nid_of(t0), m1 = nid_of(t0 + 1), m2 = nid_of(t0 + 2);
    int n3 = nid_of(t0 + 3), n4 = nid_of(t0 + 4), n5 = nid_of(t0 + 5), n6 = nid_of(t0 + 6);
    fxA = load_fx(m0); load_e2(t0 + 0, geA0, geA1);
    fxB = load_fx(m1); load_e2(t0 + 1, geB0, geB1);
    fxC = load_fx(m2); load_e2(t0 + 2, geC0, geC1);

    fxD = load_fx(n3); load_e2(t0 + 3, geD0, geD1);
    int f0 = nid_of(t0 + 7);
    layer1(fxA, geA0, geA1, T0);
    fxA = load_fx(n4); load_e2(t0 + 4, geA0, geA1);
    int f1 = nid_of(t0 + 8);
    layer1(fxB, geB0, geB1, T1); layer2(t0 + 0, T0);
    fxB = load_fx(n5); load_e2(t0 + 5, geB0, geB1);
    int f2 = nid_of(t0 + 9);
    layer1(fxC, geC0, geC1, T0); layer2(t0 + 1, T1);
    fxC = load_fx(n6); load_e2(t0 + 6, geC0, geC1);
    int f3 = nid_of(t0 + 10);
    layer1(fxD, geD0, geD1, T1); layer2(t0 + 2, T0);
    n3 = f0; n4 = f1; n5 = f2; n6 = f3;

    for (int j = 1; j < TPW_E / 4; ++j) {
        const int t = t0 + 4 * j;
        fxD = load_fx(n3); load_e2(t + 3, geD0, geD1);
        int g0 = nid_of(t + 7);
        layer1(fxA, geA0, geA1, T0); layer2(t - 1, T1);
        fxA = load_fx(n4); load_e2(t + 4, geA0, geA1);
        int g1 = nid_of(t + 8);
        layer1(fxB, geB0, geB1, T1); layer2(t + 0, T0);
        fxB = load_fx(n5); load_e2(t + 5, geB0, geB1);
        int g2 = nid_of(t + 9);
        layer1(fxC, geC0, geC1, T0); layer2(t + 1, T1);
        fxC = load_fx(n6); load_e2(t + 6, geC0, geC1);
        int g3 = nid_of(t + 10);
        layer1(fxD, geD0, geD1, T1); layer2(t + 2, T0);
        n3 = g0; n4 = g1; n5 = g2; n6 = g3;
    }
    layer2(t0 + TPW_E - 1, T1);
}

// ---------------- bprefix: one WAVE per word; packed-u8 shfl scan over 128 blocks
__global__ __launch_bounds__(256) void bprefix_kernel(
    unsigned* __restrict__ pw, unsigned* __restrict__ count)
{
    int word = blockIdx.x * 4 + (threadIdx.x >> 6);
    if (word >= NWORDS) return;
    int lane = threadIdx.x & 63;
    size_t o0 = (size_t)(2 * lane) * NWORDS + word;
    size_t o1 = (size_t)(2 * lane + 1) * NWORDS + word;
    unsigned v0 = pw[o0], v1 = pw[o1];
    unsigned s = v0 + v1;
    unsigned t = s;
#pragma unroll
    for (int d = 1; d < 64; d <<= 1) {
        unsigned u = __shfl_up(t, d, 64);
        if (lane >= d) t += u;
    }
    unsigned excl = t - s;
    pw[o0] = excl;
    pw[o1] = excl + v0;
    if (lane == 63) {
        unsigned tot = t;
        count[word * 4 + 0] = tot & 0xffu;
        count[word * 4 + 1] = (tot >> 8) & 0xffu;
        count[word * 4 + 2] = (tot >> 16) & 0xffu;
        count[word * 4 + 3] = (tot >> 24) & 0xffu;
    }
}

// ---------------- 3-phase parallel scan: count[N] -> offs[N+1]
__global__ __launch_bounds__(SCAN_BS) void scan_blocks_kernel(
    const unsigned* __restrict__ count, unsigned* __restrict__ offs,
    unsigned* __restrict__ bsum)
{
    __shared__ unsigned s[SCAN_BS];
    const int b = blockIdx.x, t = threadIdx.x;
    const int n = b * SCAN_BS + t;
    unsigned v = (n < N_NODES) ? count[n] : 0u;
    s[t] = v;
    __syncthreads();
    for (int d = 1; d < SCAN_BS; d <<= 1) {
        unsigned u = (t >= d) ? s[t - d] : 0u;
        __syncthreads();
        s[t] += u;
        __syncthreads();
    }
    if (n < N_NODES) offs[n] = s[t] - v;
    if (t == SCAN_BS - 1) bsum[b] = s[t];
}

__global__ __launch_bounds__(256) void scan_bsum_kernel(
    const unsigned* __restrict__ bsum, unsigned* __restrict__ bbase,
    unsigned* __restrict__ offs)
{
    __shared__ unsigned s[256];
    const int t = threadIdx.x;
    unsigned v = (t < SCAN_NB) ? bsum[t] : 0u;
    s[t] = v;
    __syncthreads();
    for (int d = 1; d < 256; d <<= 1) {
        unsigned u = (t >= d) ? s[t - d] : 0u;
        __syncthreads();
        s[t] += u;
        __syncthreads();
    }
    if (t < SCAN_NB) bbase[t] = s[t] - v;
    if (t == SCAN_NB - 1) offs[N_NODES] = s[t];
}

__global__ __launch_bounds__(SCAN_BS) void scan_add_kernel(
    unsigned* __restrict__ offs, const unsigned* __restrict__ bbase)
{
    const int n = blockIdx.x * SCAN_BS + threadIdx.x;
    if (n < N_NODES) offs[n] += bbase[blockIdx.x];
}

// ---------------- fill2: elist[offs[dst] + bp[b][dst] + slot8[idx]] = idx
__global__ __launch_bounds__(1024) void fill2_kernel(
    const int* __restrict__ ei, const unsigned* __restrict__ offs,
    const unsigned* __restrict__ bp_w,
    const unsigned char* __restrict__ slot8,
    unsigned* __restrict__ elist)
{
    const int b = blockIdx.x, t = threadIdx.x;
    const int base = b * CHUNK;
    const unsigned* bpb = bp_w + (size_t)b * NWORDS;
    for (int i = t; i < CHUNK; i += 1024) {
        int idx = base + i;
        int dst = ei[N_EDGES + idx];
        unsigned pre = (bpb[dst >> 2] >> ((unsigned)(dst & 3) * 8u)) & 0xffu;
        unsigned pos = offs[dst] + pre + (unsigned)slot8[idx];
        elist[pos] = (unsigned)idx;
    }
}

// ---------------- fused agg + node MLP: 3125 blocks x 16 nodes
__global__ __launch_bounds__(256) void agg_node16_kernel(
    const float* __restrict__ e_new, const unsigned* __restrict__ offs,
    const unsigned* __restrict__ elist, const float* __restrict__ x,
    const uint4* __restrict__ wtab2, float* __restrict__ x_new)
{
    __shared__ float aggl[16 * AROW];       // 1.25 KB
    __shared__ unsigned Tl[TBUF];           // 2.5 KB
    const int node0 = blockIdx.x * 16;
    const int tid = threadIdx.x;

    uint4 wq0, wq1, wq2, wq3, wq4, wq5, wq6, wq7, wq8, wq9, wq10;
    if (tid < 64) {
        wq0 = wtab2[0 * 64 + tid]; wq1 = wtab2[1 * 64 + tid];
        wq2 = wtab2[2 * 64 + tid]; wq3 = wtab2[3 * 64 + tid];
        wq4 = wtab2[4 * 64 + tid]; wq5 = wtab2[5 * 64 + tid];
        wq6 = wtab2[6 * 64 + tid]; wq7 = wtab2[7 * 64 + tid];
        wq8 = wtab2[8 * 64 + tid]; wq9 = wtab2[9 * 64 + tid];
        wq10 = wtab2[10 * 64 + tid];
    }

    {
        const int nl = tid >> 4;
        const int q  = tid & 3;
        const int r  = (tid >> 2) & 3;
        const int n  = node0 + nl;
        unsigned lo = offs[n], hi = offs[n + 1];
        const float4* ep = reinterpret_cast<const float4*>(e_new);
        float sx = 0.f, sy = 0.f, sz = 0.f, sw = 0.f;
        unsigned j = lo + r;
        unsigned eid = (j < hi) ? elist[j] : 0u;
        while (j < hi) {
            unsigned cur = eid;
            unsigned jn = j + 4;
            if (jn < hi) eid = elist[jn];
            float4 v = ep[(size_t)cur * 4 + q];
            sx += v.x; sy += v.y; sz += v.z; sw += v.w;
            j = jn;
        }
        sx += __shfl_xor(sx, 4, 64); sy += __shfl_xor(sy, 4, 64);
        sz += __shfl_xor(sz, 4, 64); sw += __shfl_xor(sw, 4, 64);
        sx += __shfl_xor(sx, 8, 64); sy += __shfl_xor(sy, 8, 64);
        sz += __shfl_xor(sz, 8, 64); sw += __shfl_xor(sw, 8, 64);
        if (r == 0)
            *reinterpret_cast<float4*>(aggl + nl * AROW + q * 4) =
                make_float4(sx, sy, sz, sw);
    }
    __syncthreads();
    if (tid >= 64) return;

    const int lane = tid;
    const int nd = lane & 15;
    const int kg = lane >> 4;
    const bool lo32 = (kg < 2);
    const int h8 = kg & 1;

    bf16x8 w1f0 = *reinterpret_cast<bf16x8*>(&wq0);
    bf16x8 w1f1 = *reinterpret_cast<bf16x8*>(&wq1);
    bf16x8 w1f2 = *reinterpret_cast<bf16x8*>(&wq2);
    bf16x8 w1f3 = *reinterpret_cast<bf16x8*>(&wq3);
    bf16x8 w2f0 = *reinterpret_cast<bf16x8*>(&wq4);
    bf16x8 w2f1 = *reinterpret_cast<bf16x8*>(&wq5);
    float4 b1v0 = *reinterpret_cast<float4*>(&wq6);
    float4 b1v1 = *reinterpret_cast<float4*>(&wq7);
    float4 b1v2 = *reinterpret_cast<float4*>(&wq8);
    float4 b1v3 = *reinterpret_cast<float4*>(&wq9);
    float4 b2v  = *reinterpret_cast<float4*>(&wq10);

    const int node = node0 + nd;
    float4 g0, g1;
    if (lo32) {
        const float4* x4 = reinterpret_cast<const float4*>(x);
        size_t o = (size_t)node * 4 + h8 * 2;
        g0 = x4[o]; g1 = x4[o + 1];
    } else {
        g0 = *reinterpret_cast<float4*>(aggl + nd * AROW + h8 * 8);
        g1 = *reinterpret_cast<float4*>(aggl + nd * AROW + h8 * 8 + 4);
    }

    union { bf16x8 v; unsigned u[4]; } fa;
    fa.u[0] = pack_bf16(g0.x, g0.y); fa.u[1] = pack_bf16(g0.z, g0.w);
    fa.u[2] = pack_bf16(g1.x, g1.y); fa.u[3] = pack_bf16(g1.z, g1.w);

    const f32x4 z = {0.f, 0.f, 0.f, 0.f};
    f32x4 acc0 = __builtin_amdgcn_mfma_f32_16x16x32_bf16(w1f0, fa.v, z, 0, 0, 0);
    f32x4 acc1 = __builtin_amdgcn_mfma_f32_16x16x32_bf16(w1f1, fa.v, z, 0, 0, 0);
    f32x4 acc2 = __builtin_amdgcn_mfma_f32_16x16x32_bf16(w1f2, fa.v, z, 0, 0, 0);
    f32x4 acc3 = __builtin_amdgcn_mfma_f32_16x16x32_bf16(w1f3, fa.v, z, 0, 0, 0);

    {
        float h0 = fmaxf(acc0[0] + b1v0.x, 0.f), h1 = fmaxf(acc0[1] + b1v0.y, 0.f);
        float h2 = fmaxf(acc0[2] + b1v0.z, 0.f), h3 = fmaxf(acc0[3] + b1v0.w, 0.f);
        Tl[(0 + 2 * kg + 0) * TROW + nd] = pack_bf16(h0, h1);
        Tl[(0 + 2 * kg + 1) * TROW + nd] = pack_bf16(h2, h3);
        h0 = fmaxf(acc1[0] + b1v1.x, 0.f); h1 = fmaxf(acc1[1] + b1v1.y, 0.f);
        h2 = fmaxf(acc1[2] + b1v1.z, 0.f); h3 = fmaxf(acc1[3] + b1v1.w, 0.f);
        Tl[(8 + 2 * kg + 0) * TROW + nd] = pack_bf16(h0, h1);
        Tl[(8 + 2 * kg + 1) * TROW + nd] = pack_bf16(h2, h3);
        h0 = fmaxf(acc2[0] + b1v2.x, 0.f); h1 = fmaxf(acc2[1] + b1v2.y, 0.f);
        h2 = fmaxf(acc2[2] + b1v2.z, 0.f); h3 = fmaxf(acc2[3] + b1v2.w, 0.f);
        Tl[(16 + 2 * kg + 0) * TROW + nd] = pack_bf16(h0, h1);
        Tl[(16 + 2 * kg + 1) * TROW + nd] = pack_bf16(h2, h3);
        h0 = fmaxf(acc3[0] + b1v3.x, 0.f); h1 = fmaxf(acc3[1] + b1v3.y, 0.f);
        h2 = fmaxf(acc3[2] + b1v3.z, 0.f); h3 = fmaxf(acc3[3] + b1v3.w, 0.f);
        Tl[(24 + 2 * kg + 0) * TROW + nd] = pack_bf16(h0, h1);
        Tl[(24 + 2 * kg + 1) * TROW + nd] = pack_bf16(h2, h3);
    }

    union { bf16x8 v; unsigned u[4]; } hf0, hf1;
#pragma unroll
    for (int j = 0; j < 4; ++j) {
        hf0.u[j] = Tl[(kg * 4 + j) * TROW + nd];
        hf1.u[j] = Tl[(16 + kg * 4 + j) * TROW + nd];
    }
    f32x4 oo = __builtin_amdgcn_mfma_f32_16x16x32_bf16(w2f0, hf0.v, z, 0, 0, 0);
    oo = __builtin_amdgcn_mfma_f32_16x16x32_bf16(w2f1, hf1.v, oo, 0, 0, 0);

    float4 st = make_float4(oo[0] + b2v.x, oo[1] + b2v.y,
                            oo[2] + b2v.z, oo[3] + b2v.w);
    *reinterpret_cast<float4*>(x_new + (size_t)node * 16 + kg * 4) = st;
}

// ---------------- legacy fallback kernels (ws too small)
__global__ __launch_bounds__(256) void edge_kernel_atomic(
    const float* __restrict__ x, const int* __restrict__ ei,
    const float* __restrict__ e,
    const float* __restrict__ W1, const float* __restrict__ b1,
    const float* __restrict__ W2, const float* __restrict__ b2,
    float* __restrict__ e_new, float* __restrict__ agg)
{
    int idx = blockIdx.x * blockDim.x + threadIdx.x;
    if (idx >= N_EDGES) return;
    int src = ei[idx];
    int dst = ei[N_EDGES + idx];
    float m[M1];
    const float4* xd = reinterpret_cast<const float4*>(x) + dst * 4;
    const float4* xs = reinterpret_cast<const float4*>(x) + src * 4;
    const float4* ep = reinterpret_cast<const float4*>(e) + (size_t)idx * 4;
#pragma unroll
    for (int q = 0; q < 4; ++q) { float4 v = xd[q]; m[4*q]=v.x; m[4*q+1]=v.y; m[4*q+2]=v.z; m[4*q+3]=v.w; }
#pragma unroll
    for (int q = 0; q < 4; ++q) { float4 v = xs[q]; m[16+4*q]=v.x; m[16+4*q+1]=v.y; m[16+4*q+2]=v.z; m[16+4*q+3]=v.w; }
#pragma unroll
    for (int q = 0; q < 4; ++q) { float4 v = ep[q]; m[32+4*q]=v.x; m[32+4*q+1]=v.y; m[32+4*q+2]=v.z; m[32+4*q+3]=v.w; }
    float h[HID];
#pragma unroll
    for (int j = 0; j < HID; ++j) h[j] = b1[j];
#pragma unroll 4
    for (int i = 0; i < M1; ++i) {
        float mi = m[i]; const float* wr = W1 + i * HID;
#pragma unroll
        for (int j = 0; j < HID; ++j) h[j] = fmaf(mi, wr[j], h[j]);
    }
    float o[ED];
#pragma unroll
    for (int k = 0; k < ED; ++k) o[k] = b2[k];
#pragma unroll 8
    for (int j = 0; j < HID; ++j) {
        float hj = fmaxf(h[j], 0.0f); const float* wr = W2 + j * ED;
#pragma unroll
        for (int k = 0; k < ED; ++k) o[k] = fmaf(hj, wr[k], o[k]);
    }
    float4* op = reinterpret_cast<float4*>(e_new) + (size_t)idx * 4;
    op[0] = make_float4(o[0],o[1],o[2],o[3]);
    op[1] = make_float4(o[4],o[5],o[6],o[7]);
    op[2] = make_float4(o[8],o[9],o[10],o[11]);
    op[3] = make_float4(o[12],o[13],o[14],o[15]);
    float* ag = agg + (size_t)dst * ED;
#pragma unroll
    for (int k = 0; k < ED; ++k) atomicAdd(ag + k, o[k]);
}

__global__ __launch_bounds__(256) void node_kernel(
    const float* __restrict__ x, const float* __restrict__ agg,
    const float* __restrict__ W1, const float* __restrict__ b1,
    const float* __restrict__ W2, const float* __restrict__ b2,
    float* __restrict__ x_new)
{
    int idx = blockIdx.x * blockDim.x + threadIdx.x;
    if (idx >= N_NODES) return;
    float m[M2];
    const float4* xp = reinterpret_cast<const float4*>(x) + idx * 4;
    const float4* ap = reinterpret_cast<const float4*>(agg) + idx * 4;
#pragma unroll
    for (int q = 0; q < 4; ++q) { float4 v = xp[q]; m[4*q]=v.x; m[4*q+1]=v.y; m[4*q+2]=v.z; m[4*q+3]=v.w; }
#pragma unroll
    for (int q = 0; q < 4; ++q) { float4 v = ap[q]; m[16+4*q]=v.x; m[16+4*q+1]=v.y; m[16+4*q+2]=v.z; m[16+4*q+3]=v.w; }
    float h[HID];
#pragma unroll
    for (int j = 0; j < HID; ++j) h[j] = b1[j];
#pragma unroll 4
    for (int i = 0; i < M2; ++i) {
        float mi = m[i]; const float* wr = W1 + i * HID;
#pragma unroll
        for (int j = 0; j < HID; ++j) h[j] = fmaf(mi, wr[j], h[j]);
    }
    float o[ED];
#pragma unroll
    for (int k = 0; k < ED; ++k) o[k] = b2[k];
#pragma unroll 8
    for (int j = 0; j < HID; ++j) {
        float hj = fmaxf(h[j], 0.0f); const float* wr = W2 + j * ED;
#pragma unroll
        for (int k = 0; k < ED; ++k) o[k] = fmaf(hj, wr[k], o[k]);
    }
    float4* op = reinterpret_cast<float4*>(x_new) + idx * 4;
    op[0] = make_float4(o[0],o[1],o[2],o[3]);
    op[1] = make_float4(o[4],o[5],o[6],o[7]);
    op[2] = make_float4(o[8],o[9],o[10],o[11]);
    op[3] = make_float4(o[12],o[13],o[14],o[15]);
}

static inline size_t align_up(size_t v, size_t a) { return (v + a - 1) / a * a; }

extern "C" void kernel_launch(void* const* d_in, const int* in_sizes, int n_in,
                              void* d_out, int out_size, void* d_ws, size_t ws_size,
                              hipStream_t stream) {
    const float* x     = (const float*)d_in[0];
    const int*   ei    = (const int*)  d_in[1];
    const float* e     = (const float*)d_in[2];
    const float* fR_W1 = (const float*)d_in[3];
    const float* fR_b1 = (const float*)d_in[4];
    const float* fR_W2 = (const float*)d_in[5];
    const float* fR_b2 = (const float*)d_in[6];
    const float* fO_W1 = (const float*)d_in[7];
    const float* fO_b1 = (const float*)d_in[8];
    const float* fO_W2 = (const float*)d_in[9];
    const float* fO_b2 = (const float*)d_in[10];

    float* x_new = (float*)d_out;                        // [N, 16]
    float* e_new = (float*)d_out + (size_t)N_NODES * ND; // [E, 16]

    char* ws = (char*)d_ws;
    size_t o = 0;
    unsigned*       offs  = (unsigned*)(ws + o);       o += align_up((size_t)(N_NODES + 1) * 4, 256);
    unsigned*       count = (unsigned*)(ws + o);       o += align_up((size_t)N_NODES * 4, 256);
    unsigned char*  slot8 = (unsigned char*)(ws + o);  o += align_up((size_t)N_EDGES, 256);
    unsigned*       pw    = (unsigned*)(ws + o);       o += align_up((size_t)NB * NWORDS * 4, 256);
    unsigned*       elist = (unsigned*)(ws + o);       o += align_up((size_t)N_EDGES * 4, 256);
    unsigned*       bsum  = (unsigned*)(ws + o);       o += align_up((size_t)SCAN_NB * 4, 256);
    unsigned*       bbase = (unsigned*)(ws + o);       o += align_up((size_t)SCAN_NB * 4, 256);
    unsigned short* xb    = (unsigned short*)(ws + o); o += align_up((size_t)N_NODES * ND * 2, 256);
    uint4*          wtab  = (uint4*)(ws + o);          o += align_up((size_t)11 * 64 * 16, 256);
    uint4*          wtab2 = (uint4*)(ws + o);          o += align_up((size_t)11 * 64 * 16, 256);
    const size_t need = o;   // ~16.4 MB

    if (ws_size >= need) {
        xw_kernel<<<XCONV_BLOCKS + 1, 256, 0, stream>>>(
            x, xb, fR_W1, fR_b1, fR_W2, fR_b2, wtab,
            fO_W1, fO_b1, fO_W2, fO_b2, wtab2);

        // fused: 128 hist blocks + 1563 edge blocks (50 KB LDS each)
        edge_hist_kernel<<<NB + EDGE_BLOCKS, 256, 0, stream>>>(
            xb, ei, e, wtab, e_new, pw, slot8);

        bprefix_kernel<<<(NWORDS + 3) / 4, 256, 0, stream>>>(pw, count);
        scan_blocks_kernel<<<SCAN_NB, SCAN_BS, 0, stream>>>(count, offs, bsum);
        scan_bsum_kernel<<<1, 256, 0, stream>>>(bsum, bbase, offs);
        scan_add_kernel<<<SCAN_NB, SCAN_BS, 0, stream>>>(offs, bbase);
        fill2_kernel<<<NB, 1024, 0, stream>>>(ei, offs, pw, slot8, elist);

        agg_node16_kernel<<<AN_BLOCKS, 256, 0, stream>>>(
            e_new, offs, elist, x, wtab2, x_new);
    } else {
        float* agg0 = (float*)d_ws;
        hipMemsetAsync(agg0, 0, (size_t)N_NODES * ED * 4, stream);
        edge_kernel_atomic<<<N_EDGES / 256, 256, 0, stream>>>(
            x, ei, e, fR_W1, fR_b1, fR_W2, fR_b2, e_new, agg0);
        node_kernel<<<(N_NODES + 255) / 256, 256, 0, stream>>>(
            x, agg0, fO_W1, fO_b1, fO_W2, fO_b2, x_new);
    }
}

// Round 19
// 148.337 us; speedup vs baseline: 1.2401x; 1.1117x over previous
//
#include <hip/hip_runtime.h>
#include <hip/hip_bf16.h>

#define N_NODES 50000
#define N_EDGES 1600000
#define ND 16
#define ED 16
#define HID 64
#define M1 (2*ND+ED)   // 48
#define M2 (ND+ED)     // 32
#define N_TILES (N_EDGES / 16)   // 100000
#define WAVES 4
#define TPW_E 16                  // tiles per wave (edge)
#define EDGE_BLOCKS ((N_TILES + WAVES*TPW_E - 1) / (WAVES*TPW_E))   // 1563

// CSR-build geometry
#define NB 128
#define CHUNK (N_EDGES / NB)     // 12500
#define NWORDS (N_NODES / 4)     // 12500 packed-u8 words

// scan geometry
#define SCAN_BS 256
#define SCAN_NB ((N_NODES + SCAN_BS - 1) / SCAN_BS)   // 196

// transpose scratch: 32 rows x 20 words (stride 20 => <=2-way banks, free)
#define TROW 20
#define TBUF (32 * TROW)

// xconv geometry
#define XCONV_BLOCKS ((N_NODES * 2 + 255) / 256)   // 391

// fused agg+node geometry: 16 nodes per block
#define AN_BLOCKS (N_NODES / 16)  // 3125
#define AROW 20

typedef short bf16x8 __attribute__((ext_vector_type(8)));
typedef float f32x4  __attribute__((ext_vector_type(4)));

__device__ inline unsigned pack_bf16(float a, float b) {
    __hip_bfloat162 p = __float22bfloat162_rn(float2{a, b});
    return *reinterpret_cast<unsigned*>(&p);
}

// ---------------- fused xconv + wprep (block-split)
__global__ __launch_bounds__(256) void xw_kernel(
    const float* __restrict__ x, unsigned short* __restrict__ xb,
    const float* __restrict__ W1, const float* __restrict__ b1,
    const float* __restrict__ W2, const float* __restrict__ b2,
    uint4* __restrict__ wtab,
    const float* __restrict__ oW1, const float* __restrict__ ob1,
    const float* __restrict__ oW2, const float* __restrict__ ob2,
    uint4* __restrict__ wtab2)
{
    if (blockIdx.x < XCONV_BLOCKS) {
        int i = blockIdx.x * 256 + threadIdx.x;
        if (i >= N_NODES * 2) return;
        const float4* xp = reinterpret_cast<const float4*>(x) + (size_t)i * 2;
        float4 a = xp[0], b = xp[1];
        uint4 o = make_uint4(pack_bf16(a.x, a.y), pack_bf16(a.z, a.w),
                             pack_bf16(b.x, b.y), pack_bf16(b.z, b.w));
        reinterpret_cast<uint4*>(xb)[i] = o;
        return;
    }
    if (threadIdx.x >= 64) return;
    const int lane = threadIdx.x;
    const int edge = lane & 15, kg = lane >> 4;
    // ---- fR table ----
#pragma unroll
    for (int t = 0; t < 4; ++t)
#pragma unroll
        for (int s = 0; s < 2; ++s) {
            union { uint4 q; unsigned u[4]; } fr;
#pragma unroll
            for (int r = 0; r < 4; ++r) {
                int k0 = s * 32 + kg * 8 + 2 * r;
                int n  = t * 16 + edge;
                float a = (k0 < M1) ? W1[k0 * HID + n] : (k0 == M1 ? b1[n] : 0.f);
                float b = (k0 + 1 < M1) ? W1[(k0 + 1) * HID + n] : 0.f;
                fr.u[r] = pack_bf16(a, b);
            }
            wtab[(t * 2 + s) * 64 + lane] = fr.q;
        }
#pragma unroll
    for (int s = 0; s < 2; ++s) {
        union { uint4 q; unsigned u[4]; } fr;
#pragma unroll
        for (int r = 0; r < 4; ++r) {
            int k0 = s * 32 + kg * 8 + 2 * r;
            fr.u[r] = pack_bf16(W2[k0 * ED + edge], W2[(k0 + 1) * ED + edge]);
        }
        wtab[(8 + s) * 64 + lane] = fr.q;
    }
    {
        float4 bb = make_float4(b2[kg * 4 + 0], b2[kg * 4 + 1],
                                b2[kg * 4 + 2], b2[kg * 4 + 3]);
        wtab[10 * 64 + lane] = *reinterpret_cast<uint4*>(&bb);
    }
    // ---- fO table ----
#pragma unroll
    for (int t = 0; t < 4; ++t) {
        union { uint4 q; unsigned u[4]; } fr;
#pragma unroll
        for (int r = 0; r < 4; ++r) {
            int k0 = kg * 8 + 2 * r;
            int n  = t * 16 + edge;
            fr.u[r] = pack_bf16(oW1[k0 * HID + n], oW1[(k0 + 1) * HID + n]);
        }
        wtab2[t * 64 + lane] = fr.q;
    }
#pragma unroll
    for (int s = 0; s < 2; ++s) {
        union { uint4 q; unsigned u[4]; } fr;
#pragma unroll
        for (int r = 0; r < 4; ++r) {
            int k0 = s * 32 + kg * 8 + 2 * r;
            fr.u[r] = pack_bf16(oW2[k0 * ED + edge], oW2[(k0 + 1) * ED + edge]);
        }
        wtab2[(4 + s) * 64 + lane] = fr.q;
    }
#pragma unroll
    for (int t = 0; t < 4; ++t) {
        float4 bb = make_float4(ob1[t * 16 + kg * 4 + 0], ob1[t * 16 + kg * 4 + 1],
                                ob1[t * 16 + kg * 4 + 2], ob1[t * 16 + kg * 4 + 3]);
        wtab2[(6 + t) * 64 + lane] = *reinterpret_cast<uint4*>(&bb);
    }
    {
        float4 bb = make_float4(ob2[kg * 4 + 0], ob2[kg * 4 + 1],
                                ob2[kg * 4 + 2], ob2[kg * 4 + 3]);
        wtab2[10 * 64 + lane] = *reinterpret_cast<uint4*>(&bb);
    }
}

// ---------------- fused edge MLP + hist (block-split, 256 threads, 50KB LDS)
__global__ __launch_bounds__(256) void edge_hist_kernel(
    const unsigned short* __restrict__ xb,  // [N,16] bf16
    const int* __restrict__ ei,
    const float* __restrict__ e,
    const uint4* __restrict__ wtab,
    float* __restrict__ e_new,
    unsigned* __restrict__ pw,              // [NB][NWORDS]
    unsigned char* __restrict__ slot8)      // [E]
{
    __shared__ __align__(16) unsigned ldsbuf[NWORDS];   // 50 KB

    if (blockIdx.x < NB) {
        // ======== hist path: single pass, 256 threads ========
        const int b = blockIdx.x, t = threadIdx.x;
        for (int w = t; w < NWORDS; w += 256) ldsbuf[w] = 0u;
        __syncthreads();
        const int base = b * CHUNK;
        for (int i = t; i < CHUNK; i += 256) {
            int idx = base + i;
            int dst = ei[N_EDGES + idx];
            unsigned sh = (unsigned)(dst & 3) * 8u;
            unsigned old = atomicAdd(&ldsbuf[dst >> 2], 1u << sh);
            slot8[idx] = (unsigned char)((old >> sh) & 0xffu);
        }
        __syncthreads();
        unsigned* out = pw + (size_t)b * NWORDS;
        for (int w = t; w < NWORDS; w += 256) out[w] = ldsbuf[w];
        return;
    }

    // ======== edge MLP path ========
    const int lane = threadIdx.x & 63;
    const int wave = threadIdx.x >> 6;
    unsigned* T0 = ldsbuf + wave * 2 * TBUF;
    unsigned* T1 = T0 + TBUF;
    const int edge = lane & 15;
    const int kg   = lane >> 4;
    const bool lo32 = (kg < 2);
    const int h8 = kg & 1;

    bf16x8 w1f[4][2];
#pragma unroll
    for (int t = 0; t < 4; ++t)
#pragma unroll
        for (int s = 0; s < 2; ++s) {
            uint4 q = wtab[(t * 2 + s) * 64 + lane];
            w1f[t][s] = *reinterpret_cast<bf16x8*>(&q);
        }
    bf16x8 w2f[2];
#pragma unroll
    for (int s = 0; s < 2; ++s) {
        uint4 q = wtab[(8 + s) * 64 + lane];
        w2f[s] = *reinterpret_cast<bf16x8*>(&q);
    }
    float4 b2v;
    {
        uint4 q = wtab[10 * 64 + lane];
        b2v = *reinterpret_cast<float4*>(&q);
    }

    const int wtile0 = (((int)blockIdx.x - NB) * WAVES + wave) * TPW_E;
    if (wtile0 >= N_TILES) return;
    const int tmax = (wtile0 + TPW_E - 1 < N_TILES - 1) ? wtile0 + TPW_E - 1 : N_TILES - 1;

    const float4* e4 = reinterpret_cast<const float4*>(e);

    auto nid_of = [&](int tl) -> int {
        int tc = tl < tmax ? tl : tmax;
        return ei[(lo32 ? N_EDGES : 0) + tc * 16 + edge];
    };
    auto load_fx = [&](int nid) -> bf16x8 {
        return *reinterpret_cast<const bf16x8*>(xb + (size_t)nid * 16 + h8 * 8);
    };
    auto load_e2 = [&](int tl, float4& a, float4& b) {
        if (lo32) {
            int tc = tl < tmax ? tl : tmax;
            size_t o = (size_t)(tc * 16 + edge) * 4 + kg * 2;
            a = e4[o]; b = e4[o + 1];
        }
    };

    auto layer1 = [&](bf16x8 fx, const float4& ge0, const float4& ge1, unsigned* T) {
        union { bf16x8 v; unsigned u[4]; } fb;
        if (lo32) {
            fb.u[0] = pack_bf16(ge0.x, ge0.y); fb.u[1] = pack_bf16(ge0.z, ge0.w);
            fb.u[2] = pack_bf16(ge1.x, ge1.y); fb.u[3] = pack_bf16(ge1.z, ge1.w);
        } else {
            fb.u[0] = (kg == 2) ? 0x00003F80u : 0u;  // k=48 -> 1.0 (bias row)
            fb.u[1] = 0u; fb.u[2] = 0u; fb.u[3] = 0u;
        }
        const f32x4 z = {0.f, 0.f, 0.f, 0.f};
        f32x4 acc[4];
        __builtin_amdgcn_s_setprio(1);
#pragma unroll
        for (int tt = 0; tt < 4; ++tt) {
            acc[tt] = __builtin_amdgcn_mfma_f32_16x16x32_bf16(w1f[tt][0], fx, z, 0, 0, 0);
            acc[tt] = __builtin_amdgcn_mfma_f32_16x16x32_bf16(w1f[tt][1], fb.v, acc[tt], 0, 0, 0);
        }
        __builtin_amdgcn_s_setprio(0);
#pragma unroll
        for (int tt = 0; tt < 4; ++tt) {
            float h0 = fmaxf(acc[tt][0], 0.f);
            float h1 = fmaxf(acc[tt][1], 0.f);
            float h2 = fmaxf(acc[tt][2], 0.f);
            float h3 = fmaxf(acc[tt][3], 0.f);
            T[(8 * tt + 2 * kg + 0) * TROW + edge] = pack_bf16(h0, h1);
            T[(8 * tt + 2 * kg + 1) * TROW + edge] = pack_bf16(h2, h3);
        }
    };

    auto layer2 = [&](int tile, const unsigned* T) {
        union { bf16x8 v; unsigned u[4]; } hf0, hf1;
#pragma unroll
        for (int j = 0; j < 4; ++j) {
            hf0.u[j] = T[(kg * 4 + j) * TROW + edge];
            hf1.u[j] = T[(16 + kg * 4 + j) * TROW + edge];
        }
        const f32x4 z = {0.f, 0.f, 0.f, 0.f};
        f32x4 o = __builtin_amdgcn_mfma_f32_16x16x32_bf16(w2f[0], hf0.v, z, 0, 0, 0);
        o = __builtin_amdgcn_mfma_f32_16x16x32_bf16(w2f[1], hf1.v, o, 0, 0, 0);
        if (tile < N_TILES) {
            float4 st = make_float4(o[0] + b2v.x, o[1] + b2v.y,
                                    o[2] + b2v.z, o[3] + b2v.w);
            *reinterpret_cast<float4*>(e_new + (size_t)(tile * 16 + edge) * 16 + kg * 4) = st;
        }
    };

    bf16x8 fxA, fxB, fxC, fxD;
    float4 geA0, geA1, geB0, geB1, geC0, geC1, geD0, geD1;

    const int t0 = wtile0;
    int m0 = nid_of(t0), m1 = nid_of(t0 + 1), m2 = nid_of(t0 + 2);
    int n3 = nid_of(t0 + 3), n4 = nid_of(t0 + 4), n5 = nid_of(t0 + 5), n6 = nid_of(t0 + 6);
    fxA = load_fx(m0); load_e2(t0 + 0, geA0, geA1);
    fxB = load_fx(m1); load_e2(t0 + 1, geB0, geB1);
    fxC = load_fx(m2); load_e2(t0 + 2, geC0, geC1);

    fxD = load_fx(n3); load_e2(t0 + 3, geD0, geD1);
    int f0 = nid_of(t0 + 7);
    layer1(fxA, geA0, geA1, T0);
    fxA = load_fx(n4); load_e2(t0 + 4, geA0, geA1);
    int f1 = nid_of(t0 + 8);
    layer1(fxB, geB0, geB1, T1); layer2(t0 + 0, T0);
    fxB = load_fx(n5); load_e2(t0 + 5, geB0, geB1);
    int f2 = nid_of(t0 + 9);
    layer1(fxC, geC0, geC1, T0); layer2(t0 + 1, T1);
    fxC = load_fx(n6); load_e2(t0 + 6, geC0, geC1);
    int f3 = nid_of(t0 + 10);
    layer1(fxD, geD0, geD1, T1); layer2(t0 + 2, T0);
    n3 = f0; n4 = f1; n5 = f2; n6 = f3;

    for (int j = 1; j < TPW_E / 4; ++j) {
        const int t = t0 + 4 * j;
        fxD = load_fx(n3); load_e2(t + 3, geD0, geD1);
        int g0 = nid_of(t + 7);
        layer1(fxA, geA0, geA1, T0); layer2(t - 1, T1);
        fxA = load_fx(n4); load_e2(t + 4, geA0, geA1);
        int g1 = nid_of(t + 8);
        layer1(fxB, geB0, geB1, T1); layer2(t + 0, T0);
        fxB = load_fx(n5); load_e2(t + 5, geB0, geB1);
        int g2 = nid_of(t + 9);
        layer1(fxC, geC0, geC1, T0); layer2(t + 1, T1);
        fxC = load_fx(n6); load_e2(t + 6, geC0, geC1);
        int g3 = nid_of(t + 10);
        layer1(fxD, geD0, geD1, T1); layer2(t + 2, T0);
        n3 = g0; n4 = g1; n5 = g2; n6 = g3;
    }
    layer2(t0 + TPW_E - 1, T1);
}

// ---------------- bprefix: one WAVE per word; packed-u8 shfl scan over 128 blocks
__global__ __launch_bounds__(256) void bprefix_kernel(
    unsigned* __restrict__ pw, unsigned* __restrict__ count)
{
    int word = blockIdx.x * 4 + (threadIdx.x >> 6);
    if (word >= NWORDS) return;
    int lane = threadIdx.x & 63;
    size_t o0 = (size_t)(2 * lane) * NWORDS + word;
    size_t o1 = (size_t)(2 * lane + 1) * NWORDS + word;
    unsigned v0 = pw[o0], v1 = pw[o1];
    unsigned s = v0 + v1;
    unsigned t = s;
#pragma unroll
    for (int d = 1; d < 64; d <<= 1) {
        unsigned u = __shfl_up(t, d, 64);
        if (lane >= d) t += u;
    }
    unsigned excl = t - s;
    pw[o0] = excl;
    pw[o1] = excl + v0;
    if (lane == 63) {
        unsigned tot = t;
        count[word * 4 + 0] = tot & 0xffu;
        count[word * 4 + 1] = (tot >> 8) & 0xffu;
        count[word * 4 + 2] = (tot >> 16) & 0xffu;
        count[word * 4 + 3] = (tot >> 24) & 0xffu;
    }
}

// ---------------- scan phase 1: per-block exclusive scan + block sums
__global__ __launch_bounds__(SCAN_BS) void scan_blocks_kernel(
    const unsigned* __restrict__ count, unsigned* __restrict__ offs,
    unsigned* __restrict__ bsum)
{
    __shared__ unsigned s[SCAN_BS];
    const int b = blockIdx.x, t = threadIdx.x;
    const int n = b * SCAN_BS + t;
    unsigned v = (n < N_NODES) ? count[n] : 0u;
    s[t] = v;
    __syncthreads();
    for (int d = 1; d < SCAN_BS; d <<= 1) {
        unsigned u = (t >= d) ? s[t - d] : 0u;
        __syncthreads();
        s[t] += u;
        __syncthreads();
    }
    if (n < N_NODES) offs[n] = s[t] - v;
    if (t == SCAN_BS - 1) bsum[b] = s[t];
}

// ---------------- scan phase 2 (merged bsum-scan + add): each block
// recomputes its own global base = sum(bsum[0..b)) via in-block reduce.
__global__ __launch_bounds__(SCAN_BS) void scan_fixup_kernel(
    const unsigned* __restrict__ bsum, unsigned* __restrict__ offs)
{
    __shared__ unsigned red[4];
    const int b = blockIdx.x, t = threadIdx.x;
    unsigned v = (t < b) ? bsum[t] : 0u;    // t<b implies t<SCAN_NB (b<=195<256)
    v += __shfl_down(v, 32, 64);
    v += __shfl_down(v, 16, 64);
    v += __shfl_down(v, 8, 64);
    v += __shfl_down(v, 4, 64);
    v += __shfl_down(v, 2, 64);
    v += __shfl_down(v, 1, 64);
    if ((t & 63) == 0) red[t >> 6] = v;
    __syncthreads();
    const unsigned base = red[0] + red[1] + red[2] + red[3];
    const int n = b * SCAN_BS + t;
    if (n < N_NODES) offs[n] += base;
    if (b == SCAN_NB - 1 && t == 0)
        offs[N_NODES] = base + bsum[SCAN_NB - 1];
}

// ---------------- fill2 (re-gridded 256x6250): elist[offs[dst]+bp[b][dst]+slot8[idx]] = idx
__global__ __launch_bounds__(256) void fill2_kernel(
    const int* __restrict__ ei, const unsigned* __restrict__ offs,
    const unsigned* __restrict__ bp_w,
    const unsigned char* __restrict__ slot8,
    unsigned* __restrict__ elist)
{
    int idx = blockIdx.x * 256 + threadIdx.x;
    if (idx >= N_EDGES) return;
    int b = idx / CHUNK;                    // hist block that owns this edge
    int dst = ei[N_EDGES + idx];
    const unsigned* bpb = bp_w + (size_t)b * NWORDS;
    unsigned pre = (bpb[dst >> 2] >> ((unsigned)(dst & 3) * 8u)) & 0xffu;
    unsigned pos = offs[dst] + pre + (unsigned)slot8[idx];
    elist[pos] = (unsigned)idx;
}

// ---------------- fused agg + node MLP: 3125 blocks x 16 nodes
__global__ __launch_bounds__(256) void agg_node16_kernel(
    const float* __restrict__ e_new, const unsigned* __restrict__ offs,
    const unsigned* __restrict__ elist, const float* __restrict__ x,
    const uint4* __restrict__ wtab2, float* __restrict__ x_new)
{
    __shared__ float aggl[16 * AROW];       // 1.25 KB
    __shared__ unsigned Tl[TBUF];           // 2.5 KB
    const int node0 = blockIdx.x * 16;
    const int tid = threadIdx.x;

    uint4 wq0, wq1, wq2, wq3, wq4, wq5, wq6, wq7, wq8, wq9, wq10;
    if (tid < 64) {
        wq0 = wtab2[0 * 64 + tid]; wq1 = wtab2[1 * 64 + tid];
        wq2 = wtab2[2 * 64 + tid]; wq3 = wtab2[3 * 64 + tid];
        wq4 = wtab2[4 * 64 + tid]; wq5 = wtab2[5 * 64 + tid];
        wq6 = wtab2[6 * 64 + tid]; wq7 = wtab2[7 * 64 + tid];
        wq8 = wtab2[8 * 64 + tid]; wq9 = wtab2[9 * 64 + tid];
        wq10 = wtab2[10 * 64 + tid];
    }

    {
        const int nl = tid >> 4;
        const int q  = tid & 3;
        const int r  = (tid >> 2) & 3;
        const int n  = node0 + nl;
        unsigned lo = offs[n], hi = offs[n + 1];
        const float4* ep = reinterpret_cast<const float4*>(e_new);
        float sx = 0.f, sy = 0.f, sz = 0.f, sw = 0.f;
        unsigned j = lo + r;
        unsigned eid = (j < hi) ? elist[j] : 0u;
        while (j < hi) {
            unsigned cur = eid;
            unsigned jn = j + 4;
            if (jn < hi) eid = elist[jn];
            float4 v = ep[(size_t)cur * 4 + q];
            sx += v.x; sy += v.y; sz += v.z; sw += v.w;
            j = jn;
        }
        sx += __shfl_xor(sx, 4, 64); sy += __shfl_xor(sy, 4, 64);
        sz += __shfl_xor(sz, 4, 64); sw += __shfl_xor(sw, 4, 64);
        sx += __shfl_xor(sx, 8, 64); sy += __shfl_xor(sy, 8, 64);
        sz += __shfl_xor(sz, 8, 64); sw += __shfl_xor(sw, 8, 64);
        if (r == 0)
            *reinterpret_cast<float4*>(aggl + nl * AROW + q * 4) =
                make_float4(sx, sy, sz, sw);
    }
    __syncthreads();
    if (tid >= 64) return;

    const int lane = tid;
    const int nd = lane & 15;
    const int kg = lane >> 4;
    const bool lo32 = (kg < 2);
    const int h8 = kg & 1;

    bf16x8 w1f0 = *reinterpret_cast<bf16x8*>(&wq0);
    bf16x8 w1f1 = *reinterpret_cast<bf16x8*>(&wq1);
    bf16x8 w1f2 = *reinterpret_cast<bf16x8*>(&wq2);
    bf16x8 w1f3 = *reinterpret_cast<bf16x8*>(&wq3);
    bf16x8 w2f0 = *reinterpret_cast<bf16x8*>(&wq4);
    bf16x8 w2f1 = *reinterpret_cast<bf16x8*>(&wq5);
    float4 b1v0 = *reinterpret_cast<float4*>(&wq6);
    float4 b1v1 = *reinterpret_cast<float4*>(&wq7);
    float4 b1v2 = *reinterpret_cast<float4*>(&wq8);
    float4 b1v3 = *reinterpret_cast<float4*>(&wq9);
    float4 b2v  = *reinterpret_cast<float4*>(&wq10);

    const int node = node0 + nd;
    float4 g0, g1;
    if (lo32) {
        const float4* x4 = reinterpret_cast<const float4*>(x);
        size_t o = (size_t)node * 4 + h8 * 2;
        g0 = x4[o]; g1 = x4[o + 1];
    } else {
        g0 = *reinterpret_cast<float4*>(aggl + nd * AROW + h8 * 8);
        g1 = *reinterpret_cast<float4*>(aggl + nd * AROW + h8 * 8 + 4);
    }

    union { bf16x8 v; unsigned u[4]; } fa;
    fa.u[0] = pack_bf16(g0.x, g0.y); fa.u[1] = pack_bf16(g0.z, g0.w);
    fa.u[2] = pack_bf16(g1.x, g1.y); fa.u[3] = pack_bf16(g1.z, g1.w);

    const f32x4 z = {0.f, 0.f, 0.f, 0.f};
    f32x4 acc0 = __builtin_amdgcn_mfma_f32_16x16x32_bf16(w1f0, fa.v, z, 0, 0, 0);
    f32x4 acc1 = __builtin_amdgcn_mfma_f32_16x16x32_bf16(w1f1, fa.v, z, 0, 0, 0);
    f32x4 acc2 = __builtin_amdgcn_mfma_f32_16x16x32_bf16(w1f2, fa.v, z, 0, 0, 0);
    f32x4 acc3 = __builtin_amdgcn_mfma_f32_16x16x32_bf16(w1f3, fa.v, z, 0, 0, 0);

    {
        float h0 = fmaxf(acc0[0] + b1v0.x, 0.f), h1 = fmaxf(acc0[1] + b1v0.y, 0.f);
        float h2 = fmaxf(acc0[2] + b1v0.z, 0.f), h3 = fmaxf(acc0[3] + b1v0.w, 0.f);
        Tl[(0 + 2 * kg + 0) * TROW + nd] = pack_bf16(h0, h1);
        Tl[(0 + 2 * kg + 1) * TROW + nd] = pack_bf16(h2, h3);
        h0 = fmaxf(acc1[0] + b1v1.x, 0.f); h1 = fmaxf(acc1[1] + b1v1.y, 0.f);
        h2 = fmaxf(acc1[2] + b1v1.z, 0.f); h3 = fmaxf(acc1[3] + b1v1.w, 0.f);
        Tl[(8 + 2 * kg + 0) * TROW + nd] = pack_bf16(h0, h1);
        Tl[(8 + 2 * kg + 1) * TROW + nd] = pack_bf16(h2, h3);
        h0 = fmaxf(acc2[0] + b1v2.x, 0.f); h1 = fmaxf(acc2[1] + b1v2.y, 0.f);
        h2 = fmaxf(acc2[2] + b1v2.z, 0.f); h3 = fmaxf(acc2[3] + b1v2.w, 0.f);
        Tl[(16 + 2 * kg + 0) * TROW + nd] = pack_bf16(h0, h1);
        Tl[(16 + 2 * kg + 1) * TROW + nd] = pack_bf16(h2, h3);
        h0 = fmaxf(acc3[0] + b1v3.x, 0.f); h1 = fmaxf(acc3[1] + b1v3.y, 0.f);
        h2 = fmaxf(acc3[2] + b1v3.z, 0.f); h3 = fmaxf(acc3[3] + b1v3.w, 0.f);
        Tl[(24 + 2 * kg + 0) * TROW + nd] = pack_bf16(h0, h1);
        Tl[(24 + 2 * kg + 1) * TROW + nd] = pack_bf16(h2, h3);
    }

    union { bf16x8 v; unsigned u[4]; } hf0, hf1;
#pragma unroll
    for (int j = 0; j < 4; ++j) {
        hf0.u[j] = Tl[(kg * 4 + j) * TROW + nd];
        hf1.u[j] = Tl[(16 + kg * 4 + j) * TROW + nd];
    }
    f32x4 oo = __builtin_amdgcn_mfma_f32_16x16x32_bf16(w2f0, hf0.v, z, 0, 0, 0);
    oo = __builtin_amdgcn_mfma_f32_16x16x32_bf16(w2f1, hf1.v, oo, 0, 0, 0);

    float4 st = make_float4(oo[0] + b2v.x, oo[1] + b2v.y,
                            oo[2] + b2v.z, oo[3] + b2v.w);
    *reinterpret_cast<float4*>(x_new + (size_t)node * 16 + kg * 4) = st;
}

// ---------------- legacy fallback kernels (ws too small)
__global__ __launch_bounds__(256) void edge_kernel_atomic(
    const float* __restrict__ x, const int* __restrict__ ei,
    const float* __restrict__ e,
    const float* __restrict__ W1, const float* __restrict__ b1,
    const float* __restrict__ W2, const float* __restrict__ b2,
    float* __restrict__ e_new, float* __restrict__ agg)
{
    int idx = blockIdx.x * blockDim.x + threadIdx.x;
    if (idx >= N_EDGES) return;
    int src = ei[idx];
    int dst = ei[N_EDGES + idx];
    float m[M1];
    const float4* xd = reinterpret_cast<const float4*>(x) + dst * 4;
    const float4* xs = reinterpret_cast<const float4*>(x) + src * 4;
    const float4* ep = reinterpret_cast<const float4*>(e) + (size_t)idx * 4;
#pragma unroll
    for (int q = 0; q < 4; ++q) { float4 v = xd[q]; m[4*q]=v.x; m[4*q+1]=v.y; m[4*q+2]=v.z; m[4*q+3]=v.w; }
#pragma unroll
    for (int q = 0; q < 4; ++q) { float4 v = xs[q]; m[16+4*q]=v.x; m[16+4*q+1]=v.y; m[16+4*q+2]=v.z; m[16+4*q+3]=v.w; }
#pragma unroll
    for (int q = 0; q < 4; ++q) { float4 v = ep[q]; m[32+4*q]=v.x; m[32+4*q+1]=v.y; m[32+4*q+2]=v.z; m[32+4*q+3]=v.w; }
    float h[HID];
#pragma unroll
    for (int j = 0; j < HID; ++j) h[j] = b1[j];
#pragma unroll 4
    for (int i = 0; i < M1; ++i) {
        float mi = m[i]; const float* wr = W1 + i * HID;
#pragma unroll
        for (int j = 0; j < HID; ++j) h[j] = fmaf(mi, wr[j], h[j]);
    }
    float o[ED];
#pragma unroll
    for (int k = 0; k < ED; ++k) o[k] = b2[k];
#pragma unroll 8
    for (int j = 0; j < HID; ++j) {
        float hj = fmaxf(h[j], 0.0f); const float* wr = W2 + j * ED;
#pragma unroll
        for (int k = 0; k < ED; ++k) o[k] = fmaf(hj, wr[k], o[k]);
    }
    float4* op = reinterpret_cast<float4*>(e_new) + (size_t)idx * 4;
    op[0] = make_float4(o[0],o[1],o[2],o[3]);
    op[1] = make_float4(o[4],o[5],o[6],o[7]);
    op[2] = make_float4(o[8],o[9],o[10],o[11]);
    op[3] = make_float4(o[12],o[13],o[14],o[15]);
    float* ag = agg + (size_t)dst * ED;
#pragma unroll
    for (int k = 0; k < ED; ++k) atomicAdd(ag + k, o[k]);
}

__global__ __launch_bounds__(256) void node_kernel(
    const float* __restrict__ x, const float* __restrict__ agg,
    const float* __restrict__ W1, const float* __restrict__ b1,
    const float* __restrict__ W2, const float* __restrict__ b2,
    float* __restrict__ x_new)
{
    int idx = blockIdx.x * blockDim.x + threadIdx.x;
    if (idx >= N_NODES) return;
    float m[M2];
    const float4* xp = reinterpret_cast<const float4*>(x) + idx * 4;
    const float4* ap = reinterpret_cast<const float4*>(agg) + idx * 4;
#pragma unroll
    for (int q = 0; q < 4; ++q) { float4 v = xp[q]; m[4*q]=v.x; m[4*q+1]=v.y; m[4*q+2]=v.z; m[4*q+3]=v.w; }
#pragma unroll
    for (int q = 0; q < 4; ++q) { float4 v = ap[q]; m[16+4*q]=v.x; m[16+4*q+1]=v.y; m[16+4*q+2]=v.z; m[16+4*q+3]=v.w; }
    float h[HID];
#pragma unroll
    for (int j = 0; j < HID; ++j) h[j] = b1[j];
#pragma unroll 4
    for (int i = 0; i < M2; ++i) {
        float mi = m[i]; const float* wr = W1 + i * HID;
#pragma unroll
        for (int j = 0; j < HID; ++j) h[j] = fmaf(mi, wr[j], h[j]);
    }
    float o[ED];
#pragma unroll
    for (int k = 0; k < ED; ++k) o[k] = b2[k];
#pragma unroll 8
    for (int j = 0; j < HID; ++j) {
        float hj = fmaxf(h[j], 0.0f); const float* wr = W2 + j * ED;
#pragma unroll
        for (int k = 0; k < ED; ++k) o[k] = fmaf(hj, wr[k], o[k]);
    }
    float4* op = reinterpret_cast<float4*>(x_new) + idx * 4;
    op[0] = make_float4(o[0],o[1],o[2],o[3]);
    op[1] = make_float4(o[4],o[5],o[6],o[7]);
    op[2] = make_float4(o[8],o[9],o[10],o[11]);
    op[3] = make_float4(o[12],o[13],o[14],o[15]);
}

static inline size_t align_up(size_t v, size_t a) { return (v + a - 1) / a * a; }

extern "C" void kernel_launch(void* const* d_in, const int* in_sizes, int n_in,
                              void* d_out, int out_size, void* d_ws, size_t ws_size,
                              hipStream_t stream) {
    const float* x     = (const float*)d_in[0];
    const int*   ei    = (const int*)  d_in[1];
    const float* e     = (const float*)d_in[2];
    const float* fR_W1 = (const float*)d_in[3];
    const float* fR_b1 = (const float*)d_in[4];
    const float* fR_W2 = (const float*)d_in[5];
    const float* fR_b2 = (const float*)d_in[6];
    const float* fO_W1 = (const float*)d_in[7];
    const float* fO_b1 = (const float*)d_in[8];
    const float* fO_W2 = (const float*)d_in[9];
    const float* fO_b2 = (const float*)d_in[10];

    float* x_new = (float*)d_out;                        // [N, 16]
    float* e_new = (float*)d_out + (size_t)N_NODES * ND; // [E, 16]

    char* ws = (char*)d_ws;
    size_t o = 0;
    unsigned*       offs  = (unsigned*)(ws + o);       o += align_up((size_t)(N_NODES + 1) * 4, 256);
    unsigned*       count = (unsigned*)(ws + o);       o += align_up((size_t)N_NODES * 4, 256);
    unsigned char*  slot8 = (unsigned char*)(ws + o);  o += align_up((size_t)N_EDGES, 256);
    unsigned*       pw    = (unsigned*)(ws + o);       o += align_up((size_t)NB * NWORDS * 4, 256);
    unsigned*       elist = (unsigned*)(ws + o);       o += align_up((size_t)N_EDGES * 4, 256);
    unsigned*       bsum  = (unsigned*)(ws + o);       o += align_up((size_t)SCAN_NB * 4, 256);
    unsigned*       bbase = (unsigned*)(ws + o);       o += align_up((size_t)SCAN_NB * 4, 256);
    unsigned short* xb    = (unsigned short*)(ws + o); o += align_up((size_t)N_NODES * ND * 2, 256);
    uint4*          wtab  = (uint4*)(ws + o);          o += align_up((size_t)11 * 64 * 16, 256);
    uint4*          wtab2 = (uint4*)(ws + o);          o += align_up((size_t)11 * 64 * 16, 256);
    const size_t need = o;   // ~16.4 MB

    if (ws_size >= need) {
        xw_kernel<<<XCONV_BLOCKS + 1, 256, 0, stream>>>(
            x, xb, fR_W1, fR_b1, fR_W2, fR_b2, wtab,
            fO_W1, fO_b1, fO_W2, fO_b2, wtab2);

        // fused: 128 hist blocks + 1563 edge blocks (50 KB LDS each)
        edge_hist_kernel<<<NB + EDGE_BLOCKS, 256, 0, stream>>>(
            xb, ei, e, wtab, e_new, pw, slot8);

        bprefix_kernel<<<(NWORDS + 3) / 4, 256, 0, stream>>>(pw, count);
        scan_blocks_kernel<<<SCAN_NB, SCAN_BS, 0, stream>>>(count, offs, bsum);
        scan_fixup_kernel<<<SCAN_NB, SCAN_BS, 0, stream>>>(bsum, offs);
        fill2_kernel<<<(N_EDGES + 255) / 256, 256, 0, stream>>>(ei, offs, pw, slot8, elist);

        agg_node16_kernel<<<AN_BLOCKS, 256, 0, stream>>>(
            e_new, offs, elist, x, wtab2, x_new);
    } else {
        float* agg0 = (float*)d_ws;
        hipMemsetAsync(agg0, 0, (size_t)N_NODES * ED * 4, stream);
        edge_kernel_atomic<<<N_EDGES / 256, 256, 0, stream>>>(
            x, ei, e, fR_W1, fR_b1, fR_W2, fR_b2, e_new, agg0);
        node_kernel<<<(N_NODES + 255) / 256, 256, 0, stream>>>(
            x, agg0, fO_W1, fO_b1, fO_W2, fO_b2, x_new);
    }
}